// Round 2
// baseline (11446.213 us; speedup 1.0000x reference)
//
#include <hip/hip_runtime.h>

#define N_   256
#define C_   64
#define T_   64
#define V_   25
#define S_   3
#define IC_  16
#define TV_  1600
#define CTV_ 102400
#define NTVf 409600.0f
#define EPS  1e-5f

__device__ __forceinline__ float lrelu(float v) { return v >= 0.f ? v : 0.1f * v; }

// -------- K0: corr[s,u,v] = sum_{c,t} x1_nets[s,c,t,u] * pe_s[c,t,v]
__global__ __launch_bounds__(256) void k0_corr(const float* __restrict__ x1s,
                                               const float* __restrict__ pe_s,
                                               float* __restrict__ corr) {
  int b = blockIdx.x; int s = b / V_, u = b % V_;
  float acc[V_];
#pragma unroll
  for (int v = 0; v < V_; ++v) acc[v] = 0.f;
  for (int idx = threadIdx.x; idx < C_ * T_; idx += 256) {
    float xv = x1s[(s * C_ * T_ + idx) * V_ + u];
    const float* per = pe_s + idx * V_;
#pragma unroll
    for (int v = 0; v < V_; ++v) acc[v] += xv * per[v];
  }
#pragma unroll
  for (int v = 0; v < V_; ++v) {
    float a = acc[v];
#pragma unroll
    for (int off = 32; off > 0; off >>= 1) a += __shfl_down(a, off);
    if ((threadIdx.x & 63) == 0) atomicAdd(&corr[(s * V_ + u) * V_ + v], a);
  }
}

// -------- K1: spatial attention matrices, one block per (n,s)
__global__ __launch_bounds__(512) void k1_att_s(
    const float* __restrict__ x, const float* __restrict__ pe_s,
    const float* __restrict__ Win_s, const float* __restrict__ bin_s,
    const float* __restrict__ x1s, const float* __restrict__ alphas,
    const float* __restrict__ betas, const float* __restrict__ att0s,
    const float* __restrict__ corr, float* __restrict__ att_s_out) {
  int n = blockIdx.x, s = blockIdx.y, tid = threadIdx.x;
  __shared__ float xpe[6400];   // [c][t(4)*25+p]  (x + pe_s)
  __shared__ float x1l[6400];   // x1_nets[s] chunk
  __shared__ float qk[3200];    // rows 0..15 = q, 16..31 = k
  float acc1[2] = {0.f, 0.f}, acc2[2] = {0.f, 0.f};
  for (int t0 = 0; t0 < T_; t0 += 4) {
    __syncthreads();
    for (int idx = tid; idx < 6400; idx += 512) {
      int c = idx / 100, p = idx % 100;
      int g = c * TV_ + t0 * V_ + p;
      xpe[idx] = x[n * CTV_ + g] + pe_s[g];
      x1l[idx] = x1s[s * CTV_ + g];
    }
    __syncthreads();
    for (int idx = tid; idx < 3200; idx += 512) {
      int r = idx / 100, p = idx % 100;
      int row = (r < IC_) ? (s * IC_ + r) : ((S_ + s) * IC_ + (r - IC_));
      const float* w = Win_s + row * C_;
      float a = bin_s[row];
#pragma unroll 8
      for (int c = 0; c < C_; ++c) a += w[c] * xpe[c * 100 + p];
      qk[idx] = a;
    }
    __syncthreads();
#pragma unroll
    for (int k = 0; k < 2; ++k) {
      int o = tid + k * 512;
      if (o < 625) {
        int u = o / V_, v = o % V_;
        float a1 = 0.f, a2 = 0.f;
#pragma unroll
        for (int t = 0; t < 4; ++t) {
          const float* qr = qk + t * 25 + u;
          const float* kr = qk + IC_ * 100 + t * 25 + v;
#pragma unroll 4
          for (int c = 0; c < IC_; ++c) a1 += qr[c * 100] * kr[c * 100];
        }
#pragma unroll
        for (int t = 0; t < 4; ++t) {
          const float* xr = x1l + t * 25 + u;
          const float* pr = xpe + t * 25 + v;
#pragma unroll 8
          for (int c = 0; c < C_; ++c) a2 += xr[c * 100] * pr[c * 100];
        }
        acc1[k] += a1; acc2[k] += a2;
      }
    }
  }
  float al = alphas[s], be = betas[s];
#pragma unroll
  for (int k = 0; k < 2; ++k) {
    int o = tid + k * 512;
    if (o < 625) {
      float a = tanhf(acc1[k] * (1.f / 1024.f)) * al
              + tanhf(acc2[k] - corr[s * 625 + o]) * be
              + att0s[s * 625 + o];
      att_s_out[(n * S_ + s) * 625 + o] = a;
    }
  }
}

// -------- K2: p1 = Wout_s @ (x (x) att_s) + bout_s ; stats1
__global__ __launch_bounds__(512) void k2_p1(
    const float* __restrict__ x, const float* __restrict__ att_s,
    const float* __restrict__ Wout_s, const float* __restrict__ bout_s,
    float* __restrict__ p1, float* __restrict__ stats) {
  int n = blockIdx.x, t0 = blockIdx.y * 4, tid = threadIdx.x;
  __shared__ float xc[6400];
  __shared__ float xa[6400];
  __shared__ float attl[1875];
  for (int idx = tid; idx < 6400; idx += 512)
    xc[idx] = x[n * CTV_ + (idx / 100) * TV_ + t0 * V_ + idx % 100];
  for (int idx = tid; idx < 1875; idx += 512) attl[idx] = att_s[n * 1875 + idx];
  int o = tid >> 3, pb = tid & 7;
  float acc[13];
#pragma unroll
  for (int j = 0; j < 13; ++j) acc[j] = 0.f;
  __syncthreads();
  for (int s = 0; s < S_; ++s) {
    if (s) __syncthreads();
    for (int idx = tid; idx < 6400; idx += 512) {
      int c = idx / 100, p = idx % 100, t = p / 25, v = p % 25;
      const float* ar = attl + s * 625 + v;
      const float* xr = xc + c * 100 + t * 25;
      float a = 0.f;
#pragma unroll
      for (int u = 0; u < V_; ++u) a += xr[u] * ar[u * 25];
      xa[idx] = a;
    }
    __syncthreads();
    const float* w = Wout_s + o * (S_ * C_) + s * C_;
#pragma unroll 8
    for (int c = 0; c < C_; ++c) {
      float wc = w[c];
      const float* xr = xa + c * 100 + pb;
#pragma unroll
      for (int j = 0; j < 13; ++j)
        if (pb + 8 * j < 100) acc[j] += wc * xr[8 * j];
    }
  }
  float b = bout_s[o], lsum = 0.f, lsq = 0.f;
  float* prow = p1 + n * CTV_ + o * TV_ + t0 * V_;
#pragma unroll
  for (int j = 0; j < 13; ++j) {
    int p = pb + 8 * j;
    if (p < 100) {
      float v = acc[j] + b;
      prow[p] = v;
      lsum += v; lsq += v * v;
    }
  }
  lsum += __shfl_down(lsum, 4); lsum += __shfl_down(lsum, 2); lsum += __shfl_down(lsum, 1);
  lsq  += __shfl_down(lsq, 4);  lsq  += __shfl_down(lsq, 2);  lsq  += __shfl_down(lsq, 1);
  if (pb == 0) { atomicAdd(&stats[o], lsum); atomicAdd(&stats[64 + o], lsq); }
}

// -------- K3: y_a = lrelu(x + bn1(p1)); p2 = Wff_s @ y_a + bff_s; stats2
__global__ __launch_bounds__(512) void k3_p2(
    const float* __restrict__ x, const float* __restrict__ p1,
    const float* __restrict__ Wff_s, const float* __restrict__ bff_s,
    const float* __restrict__ bnw1, const float* __restrict__ bnb1,
    float* __restrict__ stats, float* __restrict__ p2) {
  int n = blockIdx.x, t0 = blockIdx.y * 4, tid = threadIdx.x;
  __shared__ float ya[6400];
  __shared__ float sc[64], sh[64];
  if (tid < 64) {
    float m = stats[tid] * (1.f / NTVf);
    float var = stats[64 + tid] * (1.f / NTVf) - m * m;
    float r = rsqrtf(var + EPS);
    float scl = bnw1[tid] * r;
    sc[tid] = scl; sh[tid] = bnb1[tid] - m * scl;
  }
  __syncthreads();
  for (int idx = tid; idx < 6400; idx += 512) {
    int c = idx / 100;
    int g = n * CTV_ + c * TV_ + t0 * V_ + idx % 100;
    ya[idx] = lrelu(x[g] + p1[g] * sc[c] + sh[c]);
  }
  __syncthreads();
  int o = tid >> 3, pb = tid & 7;
  const float* w = Wff_s + o * C_;
  float acc[13];
#pragma unroll
  for (int j = 0; j < 13; ++j) acc[j] = 0.f;
#pragma unroll 8
  for (int c = 0; c < C_; ++c) {
    float wc = w[c];
    const float* xr = ya + c * 100 + pb;
#pragma unroll
    for (int j = 0; j < 13; ++j)
      if (pb + 8 * j < 100) acc[j] += wc * xr[8 * j];
  }
  float b = bff_s[o], lsum = 0.f, lsq = 0.f;
  float* prow = p2 + n * CTV_ + o * TV_ + t0 * V_;
#pragma unroll
  for (int j = 0; j < 13; ++j) {
    int p = pb + 8 * j;
    if (p < 100) {
      float v = acc[j] + b;
      prow[p] = v;
      lsum += v; lsq += v * v;
    }
  }
  lsum += __shfl_down(lsum, 4); lsum += __shfl_down(lsum, 2); lsum += __shfl_down(lsum, 1);
  lsq  += __shfl_down(lsq, 4);  lsq  += __shfl_down(lsq, 2);  lsq  += __shfl_down(lsq, 1);
  if (pb == 0) { atomicAdd(&stats[128 + o], lsum); atomicAdd(&stats[192 + o], lsq); }
}

// -------- K4a: y_b = lrelu(x + bn2(p2)) -> d_out (y_b) and transposed y_bT
__global__ __launch_bounds__(512) void k4a_yb(
    const float* __restrict__ x, const float* __restrict__ p2,
    const float* __restrict__ bnw2, const float* __restrict__ bnb2,
    const float* __restrict__ stats,
    float* __restrict__ y_b, float* __restrict__ y_bT) {
  int n = blockIdx.x, t0 = blockIdx.y * 4, tid = threadIdx.x;
  __shared__ float yb[6400];
  __shared__ float sc[64], sh[64];
  if (tid < 64) {
    float m = stats[128 + tid] * (1.f / NTVf);
    float var = stats[192 + tid] * (1.f / NTVf) - m * m;
    float r = rsqrtf(var + EPS);
    float scl = bnw2[tid] * r;
    sc[tid] = scl; sh[tid] = bnb2[tid] - m * scl;
  }
  __syncthreads();
  for (int idx = tid; idx < 6400; idx += 512) {
    int c = idx / 100, p = idx % 100;
    int g = n * CTV_ + c * TV_ + t0 * V_ + p;
    float v = lrelu(x[g] + p2[g] * sc[c] + sh[c]);
    yb[idx] = v;
    y_b[g] = v;
  }
  __syncthreads();
  for (int idx = tid; idx < 1600; idx += 512) {
    int v = idx >> 6, c = idx & 63;
    const float* yr = yb + c * 100 + v;
    float4 w4 = make_float4(yr[0], yr[25], yr[50], yr[75]);
    *(float4*)(y_bT + n * CTV_ + v * 4096 + c * 64 + t0) = w4;
  }
}

// -------- K4b: qk_s[n][r(32)][t][v] = Win_t rows for subnet s applied to (y_b + pe_t)
__global__ __launch_bounds__(512) void k4b_qk(
    const float* __restrict__ y_b, const float* __restrict__ pe_t,
    const float* __restrict__ Win_t, const float* __restrict__ bin_t,
    int s, float* __restrict__ qk) {
  int n = blockIdx.x, t0 = blockIdx.y * 4, tid = threadIdx.x;
  __shared__ float ype[6400];
  for (int idx = tid; idx < 6400; idx += 512) {
    int c = idx / 100, p = idx % 100;
    int gg = c * TV_ + t0 * V_ + p;
    ype[idx] = y_b[n * CTV_ + gg] + pe_t[gg];
  }
  __syncthreads();
  for (int idx = tid; idx < 3200; idx += 512) {
    int r = idx / 100, p = idx % 100;
    int row = (r < IC_) ? (s * IC_ + r) : ((S_ + s) * IC_ + (r - IC_));
    const float* w = Win_t + row * C_;
    float a = bin_t[row];
#pragma unroll 8
    for (int c = 0; c < C_; ++c) a += w[c] * ype[c * 100 + p];
    qk[n * 51200 + r * TV_ + t0 * V_ + p] = a;
  }
}

// -------- K5: temporal attention matrices for subnet s, one block per n
__global__ __launch_bounds__(512) void k5_att_t(
    const float* __restrict__ qk, const float* __restrict__ y_b,
    const float* __restrict__ x1t, const float* __restrict__ alphat,
    const float* __restrict__ betat, const float* __restrict__ att0t,
    int s, float* __restrict__ att_t_out) {
  int n = blockIdx.x, tid = threadIdx.x;
  __shared__ float buf[12800];
  float acc1[8], acc2[8];
#pragma unroll
  for (int j = 0; j < 8; ++j) { acc1[j] = 0.f; acc2[j] = 0.f; }
  int q = tid & 63, w8 = tid >> 6;
  for (int cc = 0; cc < 4; ++cc) {
    __syncthreads();
    const float* qb = qk + n * 51200 + (cc * 4) * TV_;
    const float* kb = qk + n * 51200 + (IC_ + cc * 4) * TV_;
    for (int idx = tid; idx < 6400; idx += 512) {
      buf[idx] = qb[idx];
      buf[6400 + idx] = kb[idx];
    }
    __syncthreads();
#pragma unroll
    for (int j = 0; j < 8; ++j) {
      int tt = j * 8 + w8;
      float a = acc1[j];
#pragma unroll
      for (int c = 0; c < 4; ++c) {
        const float* Q = buf + c * 1600 + tt * 25;
        const float* K = buf + 6400 + c * 1600 + q * 25;
#pragma unroll 5
        for (int v = 0; v < 25; ++v) a += Q[v] * K[v];
      }
      acc1[j] = a;
    }
  }
  for (int cc = 0; cc < 8; ++cc) {
    __syncthreads();
    const float* yb = y_b + n * CTV_ + cc * 8 * TV_;
    for (int idx = tid; idx < 12800; idx += 512) buf[idx] = yb[idx];
    __syncthreads();
#pragma unroll
    for (int j = 0; j < 8; ++j) {
      int tt = j * 8 + w8;
      const float* xr = x1t + s * CTV_ + cc * 8 * TV_ + tt * V_;
      float a = acc2[j];
#pragma unroll
      for (int c = 0; c < 8; ++c) {
        const float* X = xr + c * TV_;
        const float* Y = buf + c * 1600 + q * 25;
#pragma unroll 5
        for (int v = 0; v < 25; ++v) a += X[v] * Y[v];
      }
      acc2[j] = a;
    }
  }
  float al = alphat[s], be = betat[s];
#pragma unroll
  for (int j = 0; j < 8; ++j) {
    int out = (j * 8 + w8) * 64 + q;
    float a = tanhf(acc1[j] * (1.f / 400.f)) * al + tanhf(acc2[j]) * be
            + att0t[s * 4096 + out];
    att_t_out[(n * S_ + s) * 4096 + out] = a;
  }
}

// -------- K6: p3T[n][v][o][q] = Wout_t @ (sum_t y_bT * att_t) + bout_t ; stats3
__global__ __launch_bounds__(512) void k6_p3(
    const float* __restrict__ y_bT, const float* __restrict__ att_t,
    const float* __restrict__ Wout_t, const float* __restrict__ bout_t,
    float* __restrict__ p3T, float* __restrict__ stats) {
  int n = blockIdx.x, v = blockIdx.y, tid = threadIdx.x;
  __shared__ float yl[4096];       // [c][t]
  __shared__ float al[4096];       // [t][q]
  __shared__ float zt[1024];       // [ci(16)][q]
  __shared__ float wl[64 * 65];    // padded Wout_t slice [o][c]
  for (int idx = tid; idx < 4096; idx += 512)
    yl[idx] = y_bT[n * CTV_ + v * 4096 + idx];
  float acc[8];
#pragma unroll
  for (int j = 0; j < 8; ++j) acc[j] = 0.f;
  int q = tid & 63, w8 = tid >> 6;
  for (int s = 0; s < S_; ++s) {
    __syncthreads();
    for (int idx = tid; idx < 4096; idx += 512) {
      al[idx] = att_t[(n * S_ + s) * 4096 + idx];
      wl[(idx >> 6) * 65 + (idx & 63)] = Wout_t[(idx >> 6) * 192 + s * 64 + (idx & 63)];
    }
    __syncthreads();
    for (int cc = 0; cc < 4; ++cc) {
      const float* Y0 = yl + (cc * 16 + w8) * 64;
      const float* Y1 = Y0 + 8 * 64;
      float a0 = 0.f, a1 = 0.f;
#pragma unroll 8
      for (int t = 0; t < 64; ++t) {
        float av = al[t * 64 + q];
        a0 += Y0[t] * av; a1 += Y1[t] * av;
      }
      zt[w8 * 64 + q] = a0;
      zt[(8 + w8) * 64 + q] = a1;
      __syncthreads();
#pragma unroll
      for (int ci = 0; ci < 16; ++ci) {
        float zv = zt[ci * 64 + q];
#pragma unroll
        for (int j = 0; j < 8; ++j)
          acc[j] += wl[(j * 8 + w8) * 65 + cc * 16 + ci] * zv;
      }
      __syncthreads();
    }
  }
#pragma unroll
  for (int j = 0; j < 8; ++j) {
    int o = j * 8 + w8;
    float val = acc[j] + bout_t[o];
    p3T[n * CTV_ + v * 4096 + o * 64 + q] = val;
    float lsum = val, lsq = val * val;
#pragma unroll
    for (int m = 32; m > 0; m >>= 1) { lsum += __shfl_xor(lsum, m); lsq += __shfl_xor(lsq, m); }
    if (q == 0) { atomicAdd(&stats[256 + o], lsum); atomicAdd(&stats[320 + o], lsq); }
  }
}

// -------- K7: z_a = lrelu(y_bT + bn3(p3T)); p4T = Wff_t @ z_a + bff_t ; stats4
__global__ __launch_bounds__(512) void k7_p4(
    const float* __restrict__ y_bT, const float* __restrict__ p3T,
    const float* __restrict__ Wff_t, const float* __restrict__ bff_t,
    const float* __restrict__ bnw3, const float* __restrict__ bnb3,
    float* __restrict__ stats, float* __restrict__ p4T) {
  int n = blockIdx.x, v = blockIdx.y, tid = threadIdx.x;
  __shared__ float za[4096];
  __shared__ float wl[64 * 65];
  __shared__ float sc[64], sh[64];
  if (tid < 64) {
    float m = stats[256 + tid] * (1.f / NTVf);
    float var = stats[320 + tid] * (1.f / NTVf) - m * m;
    float r = rsqrtf(var + EPS);
    float scl = bnw3[tid] * r;
    sc[tid] = scl; sh[tid] = bnb3[tid] - m * scl;
  }
  __syncthreads();
  for (int idx = tid; idx < 4096; idx += 512) {
    int c = idx >> 6;
    int g = n * CTV_ + v * 4096 + idx;
    za[idx] = lrelu(y_bT[g] + p3T[g] * sc[c] + sh[c]);
    wl[(idx >> 6) * 65 + (idx & 63)] = Wff_t[idx];
  }
  __syncthreads();
  int t = tid & 63, w8 = tid >> 6;
  float acc[8];
#pragma unroll
  for (int j = 0; j < 8; ++j) acc[j] = bff_t[j * 8 + w8];
#pragma unroll 8
  for (int c = 0; c < C_; ++c) {
    float zv = za[c * 64 + t];
#pragma unroll
    for (int j = 0; j < 8; ++j) acc[j] += wl[(j * 8 + w8) * 65 + c] * zv;
  }
#pragma unroll
  for (int j = 0; j < 8; ++j) {
    int o = j * 8 + w8;
    float val = acc[j];
    p4T[n * CTV_ + v * 4096 + o * 64 + t] = val;
    float lsum = val, lsq = val * val;
#pragma unroll
    for (int m = 32; m > 0; m >>= 1) { lsum += __shfl_xor(lsum, m); lsq += __shfl_xor(lsq, m); }
    if (t == 0) { atomicAdd(&stats[384 + o], lsum); atomicAdd(&stats[448 + o], lsq); }
  }
}

// -------- K8: out = lrelu(y_b + bn4(p4)) with LDS transpose back, in-place on d_out
__global__ __launch_bounds__(512) void k8_out(
    const float* __restrict__ p4T, const float* __restrict__ bnw4,
    const float* __restrict__ bnb4, const float* __restrict__ stats,
    float* __restrict__ out) {
  int n = blockIdx.x, ct0 = blockIdx.y * 256, tid = threadIdx.x;
  __shared__ float tile[25 * 257];
  __shared__ float sc[64], sh[64];
  if (tid < 64) {
    float m = stats[384 + tid] * (1.f / NTVf);
    float var = stats[448 + tid] * (1.f / NTVf) - m * m;
    float r = rsqrtf(var + EPS);
    float scl = bnw4[tid] * r;
    sc[tid] = scl; sh[tid] = bnb4[tid] - m * scl;
  }
  for (int idx = tid; idx < 6400; idx += 512) {
    int v = idx >> 8, ctl = idx & 255;
    tile[v * 257 + ctl] = p4T[n * CTV_ + v * 4096 + ct0 + ctl];
  }
  __syncthreads();
  float* base = out + n * CTV_ + ct0 * 25;
  for (int idx = tid; idx < 6400; idx += 512) {
    int ctl = idx / 25, vv = idx % 25;
    int c = (ct0 + ctl) >> 6;
    float val = base[idx] + tile[vv * 257 + ctl] * sc[c] + sh[c];
    base[idx] = lrelu(val);
  }
}

extern "C" void kernel_launch(void* const* d_in, const int* in_sizes, int n_in,
                              void* d_out, int out_size, void* d_ws, size_t ws_size,
                              hipStream_t stream) {
  // setup_inputs() DICT order (pe_t is index 2!)
  const float* x       = (const float*)d_in[0];
  const float* pe_s    = (const float*)d_in[1];
  const float* pe_t    = (const float*)d_in[2];
  const float* Win_s   = (const float*)d_in[3];
  const float* bin_s   = (const float*)d_in[4];
  const float* alphas  = (const float*)d_in[5];
  const float* x1_nets = (const float*)d_in[6];
  const float* betas   = (const float*)d_in[7];
  const float* att0s   = (const float*)d_in[8];
  const float* Wout_s  = (const float*)d_in[9];
  const float* bout_s  = (const float*)d_in[10];
  const float* bnw1    = (const float*)d_in[11];
  const float* bnb1    = (const float*)d_in[12];
  const float* Wff_s   = (const float*)d_in[13];
  const float* bff_s   = (const float*)d_in[14];
  const float* bnw2    = (const float*)d_in[15];
  const float* bnb2    = (const float*)d_in[16];
  const float* Win_t   = (const float*)d_in[17];
  const float* bin_t   = (const float*)d_in[18];
  const float* alphat  = (const float*)d_in[19];
  const float* x1_nett = (const float*)d_in[20];
  const float* betat   = (const float*)d_in[21];
  const float* att0t   = (const float*)d_in[22];
  const float* Wout_t  = (const float*)d_in[23];
  const float* bout_t  = (const float*)d_in[24];
  const float* bnw3    = (const float*)d_in[25];
  const float* bnb3    = (const float*)d_in[26];
  const float* Wff_t   = (const float*)d_in[27];
  const float* bff_t   = (const float*)d_in[28];
  const float* bnw4    = (const float*)d_in[29];
  const float* bnb4    = (const float*)d_in[30];

  // sanity-check the dict-order assumption via element counts
  if (n_in < 31) return;
  if (in_sizes[0] != N_ * CTV_) return;        // x
  if (in_sizes[2] != CTV_) return;             // pe_t
  if (in_sizes[3] != 2 * S_ * IC_ * C_) return;// Win_s
  if (in_sizes[6] != S_ * CTV_) return;        // x1_nets
  if (in_sizes[9] != C_ * S_ * C_) return;     // Wout_s

  float* ws = (float*)d_ws;
  const size_t off_att_s = 0;                        // 480,000
  const size_t off_att_t = 480000;                   // 3,145,728
  const size_t off_corr  = off_att_t + 3145728;      // 1,875
  const size_t off_stats = off_corr + 1875;          // 512
  const size_t off_R1    = 3628160;                  // 26,214,400  p1 / qk_s / p3T
  const size_t off_R2    = off_R1 + 26214400;        // 26,214,400  p2 / p4T
  const size_t off_R3    = off_R2 + 26214400;        // 26,214,400  y_bT
  const size_t need      = (off_R3 + 26214400) * sizeof(float);  // ~329 MB
  if (ws_size < need) return;  // fail loudly via poisoned output

  float* att_s = ws + off_att_s;
  float* att_t = ws + off_att_t;
  float* corr  = ws + off_corr;
  float* stats = ws + off_stats;
  float* R1    = ws + off_R1;   // p1, then qk_s (13.1M used), then p3T
  float* R2    = ws + off_R2;   // p2, then p4T
  float* y_bT  = ws + off_R3;
  float* y_b   = (float*)d_out;

  hipMemsetAsync(corr, 0, (1875 + 512) * sizeof(float), stream);
  k0_corr<<<dim3(S_ * V_), 256, 0, stream>>>(x1_nets, pe_s, corr);
  k1_att_s<<<dim3(N_, S_), 512, 0, stream>>>(x, pe_s, Win_s, bin_s, x1_nets,
                                             alphas, betas, att0s, corr, att_s);
  k2_p1<<<dim3(N_, 16), 512, 0, stream>>>(x, att_s, Wout_s, bout_s, R1, stats);
  k3_p2<<<dim3(N_, 16), 512, 0, stream>>>(x, R1, Wff_s, bff_s, bnw1, bnb1, stats, R2);
  k4a_yb<<<dim3(N_, 16), 512, 0, stream>>>(x, R2, bnw2, bnb2, stats, y_b, y_bT);
  for (int s = 0; s < S_; ++s) {
    k4b_qk<<<dim3(N_, 16), 512, 0, stream>>>(y_b, pe_t, Win_t, bin_t, s, R1);
    k5_att_t<<<dim3(N_), 512, 0, stream>>>(R1, y_b, x1_nett, alphat, betat, att0t,
                                           s, att_t);
  }
  k6_p3<<<dim3(N_, V_), 512, 0, stream>>>(y_bT, att_t, Wout_t, bout_t, R1, stats);
  k7_p4<<<dim3(N_, V_), 512, 0, stream>>>(y_bT, R1, Wff_t, bff_t, bnw3, bnb3, stats, R2);
  k8_out<<<dim3(N_, 16), 512, 0, stream>>>(R2, bnw4, bnb4, stats, y_b);
}

// Round 3
// 8348.815 us; speedup vs baseline: 1.3710x; 1.3710x over previous
//
#include <hip/hip_runtime.h>

#define N_   256
#define C_   64
#define T_   64
#define V_   25
#define S_   3
#define IC_  16
#define TV_  1600
#define CTV_ 102400
#define NTVf 409600.0f
#define EPS  1e-5f

__device__ __forceinline__ float lrelu(float v) { return v >= 0.f ? v : 0.1f * v; }
__device__ __forceinline__ float dot4(float4 a, float4 b) {
  return a.x * b.x + a.y * b.y + a.z * b.z + a.w * b.w;
}

// -------- K0: corr[s,u,v] = sum_{c,t} x1_nets[s,c,t,u] * pe_s[c,t,v]
__global__ __launch_bounds__(256) void k0_corr(const float* __restrict__ x1s,
                                               const float* __restrict__ pe_s,
                                               float* __restrict__ corr) {
  int b = blockIdx.x; int s = b / V_, u = b % V_;
  float acc[V_];
#pragma unroll
  for (int v = 0; v < V_; ++v) acc[v] = 0.f;
  for (int idx = threadIdx.x; idx < C_ * T_; idx += 256) {
    float xv = x1s[(s * C_ * T_ + idx) * V_ + u];
    const float* per = pe_s + idx * V_;
#pragma unroll
    for (int v = 0; v < V_; ++v) acc[v] += xv * per[v];
  }
#pragma unroll
  for (int v = 0; v < V_; ++v) {
    float a = acc[v];
#pragma unroll
    for (int off = 32; off > 0; off >>= 1) a += __shfl_down(a, off);
    if ((threadIdx.x & 63) == 0) atomicAdd(&corr[(s * V_ + u) * V_ + v], a);
  }
}

// -------- K1: spatial attention matrices, one block per (n,s)
// LDS transposed tiles so every inner loop is ds_read_b128.
__global__ __launch_bounds__(512) void k1_att_s(
    const float* __restrict__ x, const float* __restrict__ pe_s,
    const float* __restrict__ Win_s, const float* __restrict__ bin_s,
    const float* __restrict__ x1s, const float* __restrict__ alphas,
    const float* __restrict__ betas, const float* __restrict__ att0s,
    const float* __restrict__ corr, float* __restrict__ att_s_out) {
  int n = blockIdx.x, s = blockIdx.y, tid = threadIdx.x;
  __shared__ alignas(16) float xpeT[100 * 68];  // [p][c]
  __shared__ alignas(16) float x1lT[100 * 68];  // [p][c]
  __shared__ alignas(16) float qkT[100 * 36];   // [p][r]  r<16:q, r>=16:k
  __shared__ alignas(16) float wls[32 * 68];    // [r][c]
  for (int idx = tid; idx < 2048; idx += 512) {
    int r = idx >> 6, c = idx & 63;
    int row = (r < IC_) ? (s * IC_ + r) : ((S_ + s) * IC_ + (r - IC_));
    wls[r * 68 + c] = Win_s[row * C_ + c];
  }
  float acc1[2] = {0.f, 0.f}, acc2[2] = {0.f, 0.f};
  for (int t0 = 0; t0 < T_; t0 += 4) {
    __syncthreads();
    for (int idx = tid; idx < 6400; idx += 512) {
      int c = idx / 100, p = idx % 100;
      int g = c * TV_ + t0 * V_ + p;
      xpeT[p * 68 + c] = x[n * CTV_ + g] + pe_s[g];
      x1lT[p * 68 + c] = x1s[s * CTV_ + g];
    }
    __syncthreads();
    for (int idx = tid; idx < 3200; idx += 512) {
      int r = idx / 100, p = idx % 100;
      int row = (r < IC_) ? (s * IC_ + r) : ((S_ + s) * IC_ + (r - IC_));
      float a = bin_s[row];
#pragma unroll
      for (int cq = 0; cq < 16; ++cq)
        a += dot4(*(const float4*)&wls[r * 68 + cq * 4],
                  *(const float4*)&xpeT[p * 68 + cq * 4]);
      qkT[p * 36 + r] = a;
    }
    __syncthreads();
#pragma unroll
    for (int k = 0; k < 2; ++k) {
      int o = tid + k * 512;
      if (o < 625) {
        int u = o / V_, v = o % V_;
        float a1 = 0.f, a2 = 0.f;
#pragma unroll
        for (int tl = 0; tl < 4; ++tl) {
          int pu = tl * 25 + u, pv = tl * 25 + v;
#pragma unroll
          for (int cq = 0; cq < 4; ++cq)
            a1 += dot4(*(const float4*)&qkT[pu * 36 + cq * 4],
                       *(const float4*)&qkT[pv * 36 + 16 + cq * 4]);
#pragma unroll
          for (int cq = 0; cq < 16; ++cq)
            a2 += dot4(*(const float4*)&x1lT[pu * 68 + cq * 4],
                       *(const float4*)&xpeT[pv * 68 + cq * 4]);
        }
        acc1[k] += a1; acc2[k] += a2;
      }
    }
  }
  float al = alphas[s], be = betas[s];
#pragma unroll
  for (int k = 0; k < 2; ++k) {
    int o = tid + k * 512;
    if (o < 625) {
      float a = tanhf(acc1[k] * (1.f / 1024.f)) * al
              + tanhf(acc2[k] - corr[s * 625 + o]) * be
              + att0s[s * 625 + o];
      att_s_out[(n * S_ + s) * 625 + o] = a;
    }
  }
}

// -------- K2: p1 = Wout_s @ (x (x) att_s) + bout_s ; stats1
__global__ __launch_bounds__(512) void k2_p1(
    const float* __restrict__ x, const float* __restrict__ att_s,
    const float* __restrict__ Wout_s, const float* __restrict__ bout_s,
    float* __restrict__ p1, float* __restrict__ stats) {
  int n = blockIdx.x, t0 = blockIdx.y * 4, tid = threadIdx.x;
  __shared__ alignas(16) float xc2[64 * 112];   // [c][t(4)*28] per-t pad for quads
  __shared__ alignas(16) float attT[25 * 28];   // [v][u]
  __shared__ alignas(16) float xaT[100 * 68];   // [p][c]
  __shared__ alignas(16) float wl[64 * 68];     // [o][c]
  for (int idx = tid; idx < 6400; idx += 512) {
    int c = idx / 100, p = idx % 100, t = p / 25, u = p % 25;
    xc2[c * 112 + t * 28 + u] = x[n * CTV_ + c * TV_ + t0 * V_ + p];
  }
  int o = tid >> 3, pb = tid & 7;
  float acc[13];
#pragma unroll
  for (int j = 0; j < 13; ++j) acc[j] = 0.f;
  for (int s = 0; s < S_; ++s) {
    __syncthreads();
    for (int idx = tid; idx < 625; idx += 512) {
      int u = idx / 25, vv = idx % 25;
      attT[vv * 28 + u] = att_s[n * 1875 + s * 625 + idx];
    }
    for (int idx = tid; idx < 4096; idx += 512) {
      int oo = idx >> 6, c = idx & 63;
      wl[oo * 68 + c] = Wout_s[oo * (S_ * C_) + s * C_ + c];
    }
    __syncthreads();
    for (int idx = tid; idx < 6400; idx += 512) {
      int c = idx / 100, p = idx % 100, t = p / 25, v = p % 25;
      const float* xr = &xc2[c * 112 + t * 28];
      const float* ar = &attT[v * 28];
      float a = 0.f;
#pragma unroll
      for (int uq = 0; uq < 6; ++uq)
        a += dot4(*(const float4*)&xr[uq * 4], *(const float4*)&ar[uq * 4]);
      a += xr[24] * ar[24];
      xaT[p * 68 + c] = a;
    }
    __syncthreads();
#pragma unroll
    for (int cq = 0; cq < 16; ++cq) {
      float4 w4 = *(const float4*)&wl[o * 68 + cq * 4];
#pragma unroll
      for (int j = 0; j < 13; ++j) {
        int p = pb + 8 * j;
        if (p < 100)
          acc[j] += dot4(w4, *(const float4*)&xaT[p * 68 + cq * 4]);
      }
    }
  }
  float b = bout_s[o], lsum = 0.f, lsq = 0.f;
  float* prow = p1 + n * CTV_ + o * TV_ + t0 * V_;
#pragma unroll
  for (int j = 0; j < 13; ++j) {
    int p = pb + 8 * j;
    if (p < 100) {
      float v = acc[j] + b;
      prow[p] = v;
      lsum += v; lsq += v * v;
    }
  }
  lsum += __shfl_down(lsum, 4); lsum += __shfl_down(lsum, 2); lsum += __shfl_down(lsum, 1);
  lsq  += __shfl_down(lsq, 4);  lsq  += __shfl_down(lsq, 2);  lsq  += __shfl_down(lsq, 1);
  if (pb == 0) { atomicAdd(&stats[o], lsum); atomicAdd(&stats[64 + o], lsq); }
}

// -------- K3: y_a = lrelu(x + bn1(p1)); p2 = Wff_s @ y_a + bff_s; stats2
__global__ __launch_bounds__(512) void k3_p2(
    const float* __restrict__ x, const float* __restrict__ p1,
    const float* __restrict__ Wff_s, const float* __restrict__ bff_s,
    const float* __restrict__ bnw1, const float* __restrict__ bnb1,
    float* __restrict__ stats, float* __restrict__ p2) {
  int n = blockIdx.x, t0 = blockIdx.y * 4, tid = threadIdx.x;
  __shared__ alignas(16) float yaT[100 * 68];  // [p][c]
  __shared__ alignas(16) float wl[64 * 68];    // [o][c]
  __shared__ float sc[64], sh[64];
  if (tid < 64) {
    float m = stats[tid] * (1.f / NTVf);
    float var = stats[64 + tid] * (1.f / NTVf) - m * m;
    float r = rsqrtf(var + EPS);
    float scl = bnw1[tid] * r;
    sc[tid] = scl; sh[tid] = bnb1[tid] - m * scl;
  }
  for (int idx = tid; idx < 4096; idx += 512) {
    int oo = idx >> 6, c = idx & 63;
    wl[oo * 68 + c] = Wff_s[idx];
  }
  __syncthreads();
  for (int idx = tid; idx < 6400; idx += 512) {
    int c = idx / 100, p = idx % 100;
    int g = n * CTV_ + c * TV_ + t0 * V_ + p;
    yaT[p * 68 + c] = lrelu(x[g] + p1[g] * sc[c] + sh[c]);
  }
  __syncthreads();
  int o = tid >> 3, pb = tid & 7;
  float acc[13];
#pragma unroll
  for (int j = 0; j < 13; ++j) acc[j] = 0.f;
#pragma unroll
  for (int cq = 0; cq < 16; ++cq) {
    float4 w4 = *(const float4*)&wl[o * 68 + cq * 4];
#pragma unroll
    for (int j = 0; j < 13; ++j) {
      int p = pb + 8 * j;
      if (p < 100)
        acc[j] += dot4(w4, *(const float4*)&yaT[p * 68 + cq * 4]);
    }
  }
  float b = bff_s[o], lsum = 0.f, lsq = 0.f;
  float* prow = p2 + n * CTV_ + o * TV_ + t0 * V_;
#pragma unroll
  for (int j = 0; j < 13; ++j) {
    int p = pb + 8 * j;
    if (p < 100) {
      float v = acc[j] + b;
      prow[p] = v;
      lsum += v; lsq += v * v;
    }
  }
  lsum += __shfl_down(lsum, 4); lsum += __shfl_down(lsum, 2); lsum += __shfl_down(lsum, 1);
  lsq  += __shfl_down(lsq, 4);  lsq  += __shfl_down(lsq, 2);  lsq  += __shfl_down(lsq, 1);
  if (pb == 0) { atomicAdd(&stats[128 + o], lsum); atomicAdd(&stats[192 + o], lsq); }
}

// -------- K4a: y_b = lrelu(x + bn2(p2)) -> d_out (y_b) and transposed y_bT
__global__ __launch_bounds__(512) void k4a_yb(
    const float* __restrict__ x, const float* __restrict__ p2,
    const float* __restrict__ bnw2, const float* __restrict__ bnb2,
    const float* __restrict__ stats,
    float* __restrict__ y_b, float* __restrict__ y_bT) {
  int n = blockIdx.x, t0 = blockIdx.y * 4, tid = threadIdx.x;
  __shared__ float yb[6400];
  __shared__ float sc[64], sh[64];
  if (tid < 64) {
    float m = stats[128 + tid] * (1.f / NTVf);
    float var = stats[192 + tid] * (1.f / NTVf) - m * m;
    float r = rsqrtf(var + EPS);
    float scl = bnw2[tid] * r;
    sc[tid] = scl; sh[tid] = bnb2[tid] - m * scl;
  }
  __syncthreads();
  for (int idx = tid; idx < 6400; idx += 512) {
    int c = idx / 100, p = idx % 100;
    int g = n * CTV_ + c * TV_ + t0 * V_ + p;
    float v = lrelu(x[g] + p2[g] * sc[c] + sh[c]);
    yb[idx] = v;
    y_b[g] = v;
  }
  __syncthreads();
  for (int idx = tid; idx < 1600; idx += 512) {
    int v = idx >> 6, c = idx & 63;
    const float* yr = yb + c * 100 + v;
    float4 w4 = make_float4(yr[0], yr[25], yr[50], yr[75]);
    *(float4*)(y_bT + n * CTV_ + v * 4096 + c * 64 + t0) = w4;
  }
}

// -------- K4b: qk[n][r(32)][t][v] for temporal subnet s
__global__ __launch_bounds__(512) void k4b_qk(
    const float* __restrict__ y_b, const float* __restrict__ pe_t,
    const float* __restrict__ Win_t, const float* __restrict__ bin_t,
    int s, float* __restrict__ qk) {
  int n = blockIdx.x, t0 = blockIdx.y * 4, tid = threadIdx.x;
  __shared__ alignas(16) float ypeT[100 * 68];  // [p][c]
  __shared__ alignas(16) float wlt[32 * 68];    // [r][c]
  for (int idx = tid; idx < 2048; idx += 512) {
    int r = idx >> 6, c = idx & 63;
    int row = (r < IC_) ? (s * IC_ + r) : ((S_ + s) * IC_ + (r - IC_));
    wlt[r * 68 + c] = Win_t[row * C_ + c];
  }
  for (int idx = tid; idx < 6400; idx += 512) {
    int c = idx / 100, p = idx % 100;
    int gg = c * TV_ + t0 * V_ + p;
    ypeT[p * 68 + c] = y_b[n * CTV_ + gg] + pe_t[gg];
  }
  __syncthreads();
  for (int idx = tid; idx < 3200; idx += 512) {
    int r = idx / 100, p = idx % 100;
    int row = (r < IC_) ? (s * IC_ + r) : ((S_ + s) * IC_ + (r - IC_));
    float a = bin_t[row];
#pragma unroll
    for (int cq = 0; cq < 16; ++cq)
      a += dot4(*(const float4*)&wlt[r * 68 + cq * 4],
                *(const float4*)&ypeT[p * 68 + cq * 4]);
    qk[n * 51200 + r * TV_ + t0 * V_ + p] = a;
  }
}

// -------- K5: temporal attention matrices for subnet s, one block per n
__global__ __launch_bounds__(512) void k5_att_t(
    const float* __restrict__ qk, const float* __restrict__ y_b,
    const float* __restrict__ x1t, const float* __restrict__ alphat,
    const float* __restrict__ betat, const float* __restrict__ att0t,
    int s, float* __restrict__ att_t_out) {
  int n = blockIdx.x, tid = threadIdx.x;
  __shared__ alignas(16) float buf[8 * 1792];  // 8 planes of [t(64)][28]
  float acc1[8], acc2[8];
#pragma unroll
  for (int j = 0; j < 8; ++j) { acc1[j] = 0.f; acc2[j] = 0.f; }
  int q = tid & 63, w8 = tid >> 6;
  // ---- QK^T part: planes 0..3 = Q(c), 4..7 = K(c)
  for (int cc = 0; cc < 4; ++cc) {
    __syncthreads();
    const float* qb = qk + n * 51200 + (cc * 4) * TV_;
    const float* kb = qk + n * 51200 + (IC_ + cc * 4) * TV_;
    for (int idx = tid; idx < 6400; idx += 512) {
      int c = idx / 1600, r = idx % 1600, t = r / 25, vv = r % 25;
      buf[c * 1792 + t * 28 + vv] = qb[idx];
      buf[(4 + c) * 1792 + t * 28 + vv] = kb[idx];
    }
    __syncthreads();
#pragma unroll
    for (int j = 0; j < 8; ++j) {
      int tt = j * 8 + w8;
      float a = acc1[j];
#pragma unroll
      for (int c = 0; c < 4; ++c) {
        const float* Q = &buf[c * 1792 + tt * 28];
        const float* K = &buf[(4 + c) * 1792 + q * 28];
#pragma unroll
        for (int vq = 0; vq < 6; ++vq)
          a += dot4(*(const float4*)&Q[vq * 4], *(const float4*)&K[vq * 4]);
        a += Q[24] * K[24];
      }
      acc1[j] = a;
    }
  }
  // ---- x1 part: planes 0..3 = Y(c), 4..7 = X1(c), 16 chunks of 4 c's
  for (int cc = 0; cc < 16; ++cc) {
    __syncthreads();
    const float* yb = y_b + n * CTV_ + cc * 4 * TV_;
    const float* xb = x1t + s * CTV_ + cc * 4 * TV_;
    for (int idx = tid; idx < 6400; idx += 512) {
      int c = idx / 1600, r = idx % 1600, t = r / 25, vv = r % 25;
      buf[c * 1792 + t * 28 + vv] = yb[idx];
      buf[(4 + c) * 1792 + t * 28 + vv] = xb[idx];
    }
    __syncthreads();
#pragma unroll
    for (int j = 0; j < 8; ++j) {
      int tt = j * 8 + w8;
      float a = acc2[j];
#pragma unroll
      for (int c = 0; c < 4; ++c) {
        const float* Y = &buf[c * 1792 + q * 28];
        const float* X = &buf[(4 + c) * 1792 + tt * 28];
#pragma unroll
        for (int vq = 0; vq < 6; ++vq)
          a += dot4(*(const float4*)&Y[vq * 4], *(const float4*)&X[vq * 4]);
        a += Y[24] * X[24];
      }
      acc2[j] = a;
    }
  }
  float al = alphat[s], be = betat[s];
#pragma unroll
  for (int j = 0; j < 8; ++j) {
    int out = (j * 8 + w8) * 64 + q;
    float a = tanhf(acc1[j] * (1.f / 400.f)) * al + tanhf(acc2[j]) * be
            + att0t[s * 4096 + out];
    att_t_out[(n * S_ + s) * 4096 + out] = a;
  }
}

// -------- K6: p3T[n][v][o][q] via two register-tiled GEMMs ; stats3
__global__ __launch_bounds__(512) void k6_p3(
    const float* __restrict__ y_bT, const float* __restrict__ att_t,
    const float* __restrict__ Wout_t, const float* __restrict__ bout_t,
    float* __restrict__ p3T, float* __restrict__ stats) {
  int n = blockIdx.x, v = blockIdx.y, tid = threadIdx.x;
  int q = tid & 63, w8 = tid >> 6;
  __shared__ alignas(16) float yl[64 * 68];  // Y[c][t]
  __shared__ alignas(16) float aT[64 * 68];  // A_s^T [q][t]
  __shared__ alignas(16) float wl[64 * 68];  // W[o][c] slice for s
  __shared__ float zs[64 * 65];              // Z_s[c][q]
  for (int idx = tid; idx < 4096; idx += 512) {
    int c = idx >> 6, t = idx & 63;
    yl[c * 68 + t] = y_bT[n * CTV_ + v * 4096 + idx];
  }
  float acc[8];
#pragma unroll
  for (int j = 0; j < 8; ++j) acc[j] = 0.f;
  for (int s = 0; s < S_; ++s) {
    __syncthreads();
    for (int idx = tid; idx < 4096; idx += 512) {
      int t = idx >> 6, qq = idx & 63;
      aT[qq * 68 + t] = att_t[(n * S_ + s) * 4096 + idx];
      int oo = idx >> 6, c = idx & 63;
      wl[oo * 68 + c] = Wout_t[oo * 192 + s * 64 + c];
    }
    __syncthreads();
    // GEMM1: Z[c][q] = sum_t Y[c][t] * A[t][q], thread owns c = w8+8k, col q
    float accz[8];
#pragma unroll
    for (int k = 0; k < 8; ++k) accz[k] = 0.f;
#pragma unroll
    for (int tq = 0; tq < 16; ++tq) {
      float4 a4 = *(const float4*)&aT[q * 68 + tq * 4];
#pragma unroll
      for (int k = 0; k < 8; ++k)
        accz[k] += dot4(*(const float4*)&yl[(w8 + 8 * k) * 68 + tq * 4], a4);
    }
#pragma unroll
    for (int k = 0; k < 8; ++k) zs[(w8 + 8 * k) * 65 + q] = accz[k];
    __syncthreads();
    // GEMM2: acc[j] += sum_c W[o=w8+8j][c] * Z[c][q]
#pragma unroll
    for (int cq = 0; cq < 16; ++cq) {
      float z0 = zs[(cq * 4 + 0) * 65 + q];
      float z1 = zs[(cq * 4 + 1) * 65 + q];
      float z2 = zs[(cq * 4 + 2) * 65 + q];
      float z3 = zs[(cq * 4 + 3) * 65 + q];
#pragma unroll
      for (int j = 0; j < 8; ++j) {
        float4 w4 = *(const float4*)&wl[(w8 + 8 * j) * 68 + cq * 4];
        acc[j] += w4.x * z0 + w4.y * z1 + w4.z * z2 + w4.w * z3;
      }
    }
  }
#pragma unroll
  for (int j = 0; j < 8; ++j) {
    int o = w8 + 8 * j;
    float val = acc[j] + bout_t[o];
    p3T[n * CTV_ + v * 4096 + o * 64 + q] = val;
    float lsum = val, lsq = val * val;
#pragma unroll
    for (int m = 32; m > 0; m >>= 1) { lsum += __shfl_xor(lsum, m); lsq += __shfl_xor(lsq, m); }
    if (q == 0) { atomicAdd(&stats[256 + o], lsum); atomicAdd(&stats[320 + o], lsq); }
  }
}

// -------- K7: z_a = lrelu(y_bT + bn3(p3T)); p4T = Wff_t @ z_a + bff_t ; stats4
__global__ __launch_bounds__(512) void k7_p4(
    const float* __restrict__ y_bT, const float* __restrict__ p3T,
    const float* __restrict__ Wff_t, const float* __restrict__ bff_t,
    const float* __restrict__ bnw3, const float* __restrict__ bnb3,
    float* __restrict__ stats, float* __restrict__ p4T) {
  int n = blockIdx.x, v = blockIdx.y, tid = threadIdx.x;
  int q = tid & 63, w8 = tid >> 6;
  __shared__ alignas(16) float zaT[64 * 68];  // [t][c]
  __shared__ alignas(16) float wl[64 * 68];   // [o][c]
  __shared__ float sc[64], sh[64];
  if (tid < 64) {
    float m = stats[256 + tid] * (1.f / NTVf);
    float var = stats[320 + tid] * (1.f / NTVf) - m * m;
    float r = rsqrtf(var + EPS);
    float scl = bnw3[tid] * r;
    sc[tid] = scl; sh[tid] = bnb3[tid] - m * scl;
  }
  for (int idx = tid; idx < 4096; idx += 512) {
    int oo = idx >> 6, c = idx & 63;
    wl[oo * 68 + c] = Wff_t[idx];
  }
  __syncthreads();
  for (int idx = tid; idx < 4096; idx += 512) {
    int c = idx >> 6, t = idx & 63;
    int g = n * CTV_ + v * 4096 + idx;
    zaT[t * 68 + c] = lrelu(y_bT[g] + p3T[g] * sc[c] + sh[c]);
  }
  __syncthreads();
  float acc[8];
#pragma unroll
  for (int j = 0; j < 8; ++j) acc[j] = bff_t[w8 + 8 * j];
#pragma unroll
  for (int cq = 0; cq < 16; ++cq) {
    float4 zq = *(const float4*)&zaT[q * 68 + cq * 4];
#pragma unroll
    for (int j = 0; j < 8; ++j) {
      float4 w4 = *(const float4*)&wl[(w8 + 8 * j) * 68 + cq * 4];
      acc[j] += dot4(w4, zq);
    }
  }
#pragma unroll
  for (int j = 0; j < 8; ++j) {
    int o = w8 + 8 * j;
    float val = acc[j];
    p4T[n * CTV_ + v * 4096 + o * 64 + q] = val;
    float lsum = val, lsq = val * val;
#pragma unroll
    for (int m = 32; m > 0; m >>= 1) { lsum += __shfl_xor(lsum, m); lsq += __shfl_xor(lsq, m); }
    if (q == 0) { atomicAdd(&stats[384 + o], lsum); atomicAdd(&stats[448 + o], lsq); }
  }
}

// -------- K8: out = lrelu(y_b + bn4(p4)) with LDS transpose back, in-place on d_out
__global__ __launch_bounds__(512) void k8_out(
    const float* __restrict__ p4T, const float* __restrict__ bnw4,
    const float* __restrict__ bnb4, const float* __restrict__ stats,
    float* __restrict__ out) {
  int n = blockIdx.x, ct0 = blockIdx.y * 256, tid = threadIdx.x;
  __shared__ float tile[25 * 257];
  __shared__ float sc[64], sh[64];
  if (tid < 64) {
    float m = stats[384 + tid] * (1.f / NTVf);
    float var = stats[448 + tid] * (1.f / NTVf) - m * m;
    float r = rsqrtf(var + EPS);
    float scl = bnw4[tid] * r;
    sc[tid] = scl; sh[tid] = bnb4[tid] - m * scl;
  }
  for (int idx = tid; idx < 6400; idx += 512) {
    int v = idx >> 8, ctl = idx & 255;
    tile[v * 257 + ctl] = p4T[n * CTV_ + v * 4096 + ct0 + ctl];
  }
  __syncthreads();
  float* base = out + n * CTV_ + ct0 * 25;
  for (int idx = tid; idx < 6400; idx += 512) {
    int ctl = idx / 25, vv = idx % 25;
    int c = (ct0 + ctl) >> 6;
    float val = base[idx] + tile[vv * 257 + ctl] * sc[c] + sh[c];
    base[idx] = lrelu(val);
  }
}

extern "C" void kernel_launch(void* const* d_in, const int* in_sizes, int n_in,
                              void* d_out, int out_size, void* d_ws, size_t ws_size,
                              hipStream_t stream) {
  // setup_inputs() DICT order (pe_t is index 2!)
  const float* x       = (const float*)d_in[0];
  const float* pe_s    = (const float*)d_in[1];
  const float* pe_t    = (const float*)d_in[2];
  const float* Win_s   = (const float*)d_in[3];
  const float* bin_s   = (const float*)d_in[4];
  const float* alphas  = (const float*)d_in[5];
  const float* x1_nets = (const float*)d_in[6];
  const float* betas   = (const float*)d_in[7];
  const float* att0s   = (const float*)d_in[8];
  const float* Wout_s  = (const float*)d_in[9];
  const float* bout_s  = (const float*)d_in[10];
  const float* bnw1    = (const float*)d_in[11];
  const float* bnb1    = (const float*)d_in[12];
  const float* Wff_s   = (const float*)d_in[13];
  const float* bff_s   = (const float*)d_in[14];
  const float* bnw2    = (const float*)d_in[15];
  const float* bnb2    = (const float*)d_in[16];
  const float* Win_t   = (const float*)d_in[17];
  const float* bin_t   = (const float*)d_in[18];
  const float* alphat  = (const float*)d_in[19];
  const float* x1_nett = (const float*)d_in[20];
  const float* betat   = (const float*)d_in[21];
  const float* att0t   = (const float*)d_in[22];
  const float* Wout_t  = (const float*)d_in[23];
  const float* bout_t  = (const float*)d_in[24];
  const float* bnw3    = (const float*)d_in[25];
  const float* bnb3    = (const float*)d_in[26];
  const float* Wff_t   = (const float*)d_in[27];
  const float* bff_t   = (const float*)d_in[28];
  const float* bnw4    = (const float*)d_in[29];
  const float* bnb4    = (const float*)d_in[30];

  if (n_in < 31) return;
  if (in_sizes[0] != N_ * CTV_) return;
  if (in_sizes[2] != CTV_) return;
  if (in_sizes[3] != 2 * S_ * IC_ * C_) return;
  if (in_sizes[6] != S_ * CTV_) return;
  if (in_sizes[9] != C_ * S_ * C_) return;

  float* ws = (float*)d_ws;
  const size_t off_att_s = 0;
  const size_t off_att_t = 480000;
  const size_t off_corr  = off_att_t + 3145728;
  const size_t off_stats = off_corr + 1875;
  const size_t off_R1    = 3628160;
  const size_t off_R2    = off_R1 + 26214400;
  const size_t off_R3    = off_R2 + 26214400;
  const size_t need      = (off_R3 + 26214400) * sizeof(float);
  if (ws_size < need) return;

  float* att_s = ws + off_att_s;
  float* att_t = ws + off_att_t;
  float* corr  = ws + off_corr;
  float* stats = ws + off_stats;
  float* R1    = ws + off_R1;   // p1, then qk (13.1M used), then p3T
  float* R2    = ws + off_R2;   // p2, then p4T
  float* y_bT  = ws + off_R3;
  float* y_b   = (float*)d_out;

  hipMemsetAsync(corr, 0, (1875 + 512) * sizeof(float), stream);
  k0_corr<<<dim3(S_ * V_), 256, 0, stream>>>(x1_nets, pe_s, corr);
  k1_att_s<<<dim3(N_, S_), 512, 0, stream>>>(x, pe_s, Win_s, bin_s, x1_nets,
                                             alphas, betas, att0s, corr, att_s);
  k2_p1<<<dim3(N_, 16), 512, 0, stream>>>(x, att_s, Wout_s, bout_s, R1, stats);
  k3_p2<<<dim3(N_, 16), 512, 0, stream>>>(x, R1, Wff_s, bff_s, bnw1, bnb1, stats, R2);
  k4a_yb<<<dim3(N_, 16), 512, 0, stream>>>(x, R2, bnw2, bnb2, stats, y_b, y_bT);
  for (int s = 0; s < S_; ++s) {
    k4b_qk<<<dim3(N_, 16), 512, 0, stream>>>(y_b, pe_t, Win_t, bin_t, s, R1);
    k5_att_t<<<dim3(N_), 512, 0, stream>>>(R1, y_b, x1_nett, alphat, betat, att0t,
                                           s, att_t);
  }
  k6_p3<<<dim3(N_, V_), 512, 0, stream>>>(y_bT, att_t, Wout_t, bout_t, R1, stats);
  k7_p4<<<dim3(N_, V_), 512, 0, stream>>>(y_bT, R1, Wff_t, bff_t, bnw3, bnb3, stats, R2);
  k8_out<<<dim3(N_, 16), 512, 0, stream>>>(R2, bnw4, bnb4, stats, y_b);
}

// Round 5
// 6819.661 us; speedup vs baseline: 1.6784x; 1.2242x over previous
//
#include <hip/hip_runtime.h>

#define N_   256
#define C_   64
#define T_   64
#define V_   25
#define S_   3
#define IC_  16
#define TV_  1600
#define CTV_ 102400
#define NTVf 409600.0f
#define EPS  1e-5f

__device__ __forceinline__ float lrelu(float v) { return v >= 0.f ? v : 0.1f * v; }
__device__ __forceinline__ float dot4(float4 a, float4 b) {
  return a.x * b.x + a.y * b.y + a.z * b.z + a.w * b.w;
}
// swizzled slot offsets: row stride 64 floats (16 quads) / 32 floats (8 quads)
__device__ __forceinline__ int sw64(int row, int q) { return (q ^ (row & 15)) << 2; }
__device__ __forceinline__ int sw32(int row, int q) { return (q ^ (row & 7)) << 2; }

// -------- kred: stats[ch] = sum_i part[i*128 + ch], ch in [0,128)
__global__ __launch_bounds__(256) void kred(const float* __restrict__ part, int nblk,
                                            float* __restrict__ out) {
  int ch = blockIdx.x;
  float a = 0.f;
  for (int i = threadIdx.x; i < nblk; i += 256) a += part[i * 128 + ch];
  __shared__ float red[4];
#pragma unroll
  for (int off = 32; off > 0; off >>= 1) a += __shfl_down(a, off);
  if ((threadIdx.x & 63) == 0) red[threadIdx.x >> 6] = a;
  __syncthreads();
  if (threadIdx.x == 0) out[ch] = red[0] + red[1] + red[2] + red[3];
}

// -------- K0: corr[s,u,v] = sum_{c,t} x1_nets[s,c,t,u] * pe_s[c,t,v]
__global__ __launch_bounds__(256) void k0_corr(const float* __restrict__ x1s,
                                               const float* __restrict__ pe_s,
                                               float* __restrict__ corr) {
  int b = blockIdx.x; int s = b / V_, u = b % V_;
  float acc[V_];
#pragma unroll
  for (int v = 0; v < V_; ++v) acc[v] = 0.f;
  for (int idx = threadIdx.x; idx < C_ * T_; idx += 256) {
    float xv = x1s[(s * C_ * T_ + idx) * V_ + u];
    const float* per = pe_s + idx * V_;
#pragma unroll
    for (int v = 0; v < V_; ++v) acc[v] += xv * per[v];
  }
#pragma unroll
  for (int v = 0; v < V_; ++v) {
    float a = acc[v];
#pragma unroll
    for (int off = 32; off > 0; off >>= 1) a += __shfl_down(a, off);
    if ((threadIdx.x & 63) == 0) atomicAdd(&corr[(s * V_ + u) * V_ + v], a);
  }
}

// -------- K1: spatial attention matrices, one block per (n,s). Swizzled LDS.
__global__ __launch_bounds__(512) void k1_att_s(
    const float* __restrict__ x, const float* __restrict__ pe_s,
    const float* __restrict__ Win_s, const float* __restrict__ bin_s,
    const float* __restrict__ x1s, const float* __restrict__ alphas,
    const float* __restrict__ betas, const float* __restrict__ att0s,
    const float* __restrict__ corr, float* __restrict__ att_s_out) {
  int n = blockIdx.x, s = blockIdx.y, tid = threadIdx.x;
  __shared__ alignas(16) float xpeT[100 * 64];  // [p][c-swz]
  __shared__ alignas(16) float x1lT[100 * 64];  // [p][c-swz]
  __shared__ alignas(16) float qkT[100 * 32];   // [p][r-swz] r<16:q r>=16:k
  __shared__ alignas(16) float wls[32 * 64];    // [r][c] (broadcast rows)
  for (int idx = tid; idx < 2048; idx += 512) {
    int r = idx >> 6, c = idx & 63;
    int row = (r < IC_) ? (s * IC_ + r) : ((S_ + s) * IC_ + (r - IC_));
    wls[r * 64 + c] = Win_s[row * C_ + c];
  }
  float acc1[2] = {0.f, 0.f}, acc2[2] = {0.f, 0.f};
  for (int t0 = 0; t0 < T_; t0 += 4) {
    __syncthreads();
    for (int idx = tid; idx < 6400; idx += 512) {
      int c = idx / 100, p = idx % 100;
      int g = c * TV_ + t0 * V_ + p;
      int a = p * 64 + sw64(p, c >> 2) + (c & 3);
      xpeT[a] = x[n * CTV_ + g] + pe_s[g];
      x1lT[a] = x1s[s * CTV_ + g];
    }
    __syncthreads();
    for (int idx = tid; idx < 3200; idx += 512) {
      int r = idx / 100, p = idx % 100;
      int row = (r < IC_) ? (s * IC_ + r) : ((S_ + s) * IC_ + (r - IC_));
      float a = bin_s[row];
#pragma unroll
      for (int cq = 0; cq < 16; ++cq)
        a += dot4(*(const float4*)&wls[r * 64 + cq * 4],
                  *(const float4*)&xpeT[p * 64 + sw64(p, cq)]);
      qkT[p * 32 + sw32(p, r >> 2) + (r & 3)] = a;
    }
    __syncthreads();
#pragma unroll
    for (int k = 0; k < 2; ++k) {
      int o = tid + k * 512;
      if (o < 625) {
        int u = o / V_, v = o % V_;
        float a1 = 0.f, a2 = 0.f;
#pragma unroll
        for (int tl = 0; tl < 4; ++tl) {
          int pu = tl * 25 + u, pv = tl * 25 + v;
#pragma unroll
          for (int cq = 0; cq < 4; ++cq)
            a1 += dot4(*(const float4*)&qkT[pu * 32 + sw32(pu, cq)],
                       *(const float4*)&qkT[pv * 32 + sw32(pv, cq + 4)]);
#pragma unroll
          for (int cq = 0; cq < 16; ++cq)
            a2 += dot4(*(const float4*)&x1lT[pu * 64 + sw64(pu, cq)],
                       *(const float4*)&xpeT[pv * 64 + sw64(pv, cq)]);
        }
        acc1[k] += a1; acc2[k] += a2;
      }
    }
  }
  float al = alphas[s], be = betas[s];
#pragma unroll
  for (int k = 0; k < 2; ++k) {
    int o = tid + k * 512;
    if (o < 625) {
      float a = tanhf(acc1[k] * (1.f / 1024.f)) * al
              + tanhf(acc2[k] - corr[s * 625 + o]) * be
              + att0s[s * 625 + o];
      att_s_out[(n * S_ + s) * 625 + o] = a;
    }
  }
}

// -------- K2: p1 = Wout_s @ (x (x) att_s) + bout_s ; partial stats
__global__ __launch_bounds__(512) void k2_p1(
    const float* __restrict__ x, const float* __restrict__ att_s,
    const float* __restrict__ Wout_s, const float* __restrict__ bout_s,
    float* __restrict__ p1, float* __restrict__ part) {
  int n = blockIdx.x, t0 = blockIdx.y * 4, tid = threadIdx.x;
  __shared__ alignas(16) float xc2[64 * 112];   // [c][t*28+u] broadcast rows
  __shared__ alignas(16) float attT[25 * 32];   // [v][u-swz]
  __shared__ alignas(16) float xaT[100 * 68];   // [p][c] (p mod-8 distinct: free)
  __shared__ alignas(16) float wl[64 * 68];     // [o][c]
  for (int idx = tid; idx < 6400; idx += 512) {
    int c = idx / 100, p = idx % 100, t = p / 25, u = p % 25;
    xc2[c * 112 + t * 28 + u] = x[n * CTV_ + c * TV_ + t0 * V_ + p];
  }
  int o = tid >> 3, pb = tid & 7;
  float acc[13];
#pragma unroll
  for (int j = 0; j < 13; ++j) acc[j] = 0.f;
  for (int s = 0; s < S_; ++s) {
    __syncthreads();
    for (int idx = tid; idx < 625; idx += 512) {
      int u = idx / 25, vv = idx % 25;
      attT[vv * 32 + sw32(vv, u >> 2) + (u & 3)] = att_s[n * 1875 + s * 625 + idx];
    }
    for (int idx = tid; idx < 4096; idx += 512) {
      int oo = idx >> 6, c = idx & 63;
      wl[oo * 68 + c] = Wout_s[oo * (S_ * C_) + s * C_ + c];
    }
    __syncthreads();
    for (int idx = tid; idx < 6400; idx += 512) {
      int c = idx / 100, p = idx % 100, t = p / 25, v = p % 25;
      const float* xr = &xc2[c * 112 + t * 28];
      const float* ar = &attT[v * 32];
      float a = 0.f;
#pragma unroll
      for (int uq = 0; uq < 6; ++uq)
        a += dot4(*(const float4*)&xr[uq * 4], *(const float4*)&ar[sw32(v, uq)]);
      a += xr[24] * ar[sw32(v, 6)];
      xaT[p * 68 + c] = a;
    }
    __syncthreads();
#pragma unroll
    for (int cq = 0; cq < 16; ++cq) {
      float4 w4 = *(const float4*)&wl[o * 68 + cq * 4];
#pragma unroll
      for (int j = 0; j < 13; ++j) {
        int p = pb + 8 * j;
        if (p < 100)
          acc[j] += dot4(w4, *(const float4*)&xaT[p * 68 + cq * 4]);
      }
    }
  }
  float b = bout_s[o], lsum = 0.f, lsq = 0.f;
  float* prow = p1 + n * CTV_ + o * TV_ + t0 * V_;
#pragma unroll
  for (int j = 0; j < 13; ++j) {
    int p = pb + 8 * j;
    if (p < 100) {
      float v = acc[j] + b;
      prow[p] = v;
      lsum += v; lsq += v * v;
    }
  }
  lsum += __shfl_down(lsum, 4); lsum += __shfl_down(lsum, 2); lsum += __shfl_down(lsum, 1);
  lsq  += __shfl_down(lsq, 4);  lsq  += __shfl_down(lsq, 2);  lsq  += __shfl_down(lsq, 1);
  if (pb == 0) {
    int bid = blockIdx.x * 16 + blockIdx.y;
    part[bid * 128 + o] = lsum;
    part[bid * 128 + 64 + o] = lsq;
  }
}

// -------- K3: y_a = lrelu(x + bn1(p1)); p2 = Wff_s @ y_a + bff_s; partial stats
__global__ __launch_bounds__(512) void k3_p2(
    const float* __restrict__ x, const float* __restrict__ p1,
    const float* __restrict__ Wff_s, const float* __restrict__ bff_s,
    const float* __restrict__ bnw1, const float* __restrict__ bnb1,
    const float* __restrict__ stats, float* __restrict__ p2,
    float* __restrict__ part) {
  int n = blockIdx.x, t0 = blockIdx.y * 4, tid = threadIdx.x;
  __shared__ alignas(16) float yaT[100 * 68];
  __shared__ alignas(16) float wl[64 * 68];
  __shared__ float sc[64], sh[64];
  if (tid < 64) {
    float m = stats[tid] * (1.f / NTVf);
    float var = stats[64 + tid] * (1.f / NTVf) - m * m;
    float r = rsqrtf(var + EPS);
    float scl = bnw1[tid] * r;
    sc[tid] = scl; sh[tid] = bnb1[tid] - m * scl;
  }
  for (int idx = tid; idx < 4096; idx += 512) {
    int oo = idx >> 6, c = idx & 63;
    wl[oo * 68 + c] = Wff_s[idx];
  }
  __syncthreads();
  for (int idx = tid; idx < 6400; idx += 512) {
    int c = idx / 100, p = idx % 100;
    int g = n * CTV_ + c * TV_ + t0 * V_ + p;
    yaT[p * 68 + c] = lrelu(x[g] + p1[g] * sc[c] + sh[c]);
  }
  __syncthreads();
  int o = tid >> 3, pb = tid & 7;
  float acc[13];
#pragma unroll
  for (int j = 0; j < 13; ++j) acc[j] = 0.f;
#pragma unroll
  for (int cq = 0; cq < 16; ++cq) {
    float4 w4 = *(const float4*)&wl[o * 68 + cq * 4];
#pragma unroll
    for (int j = 0; j < 13; ++j) {
      int p = pb + 8 * j;
      if (p < 100)
        acc[j] += dot4(w4, *(const float4*)&yaT[p * 68 + cq * 4]);
    }
  }
  float b = bff_s[o], lsum = 0.f, lsq = 0.f;
  float* prow = p2 + n * CTV_ + o * TV_ + t0 * V_;
#pragma unroll
  for (int j = 0; j < 13; ++j) {
    int p = pb + 8 * j;
    if (p < 100) {
      float v = acc[j] + b;
      prow[p] = v;
      lsum += v; lsq += v * v;
    }
  }
  lsum += __shfl_down(lsum, 4); lsum += __shfl_down(lsum, 2); lsum += __shfl_down(lsum, 1);
  lsq  += __shfl_down(lsq, 4);  lsq  += __shfl_down(lsq, 2);  lsq  += __shfl_down(lsq, 1);
  if (pb == 0) {
    int bid = blockIdx.x * 16 + blockIdx.y;
    part[bid * 128 + o] = lsum;
    part[bid * 128 + 64 + o] = lsq;
  }
}

// -------- K4a: y_b = lrelu(x + bn2(p2)) -> d_out (y_b) and transposed y_bT
__global__ __launch_bounds__(512) void k4a_yb(
    const float* __restrict__ x, const float* __restrict__ p2,
    const float* __restrict__ bnw2, const float* __restrict__ bnb2,
    const float* __restrict__ stats,
    float* __restrict__ y_b, float* __restrict__ y_bT) {
  int n = blockIdx.x, t0 = blockIdx.y * 4, tid = threadIdx.x;
  __shared__ float yb[64 * 101];  // stride 101: conflict-free strided reads
  __shared__ float sc[64], sh[64];
  if (tid < 64) {
    float m = stats[128 + tid] * (1.f / NTVf);
    float var = stats[192 + tid] * (1.f / NTVf) - m * m;
    float r = rsqrtf(var + EPS);
    float scl = bnw2[tid] * r;
    sc[tid] = scl; sh[tid] = bnb2[tid] - m * scl;
  }
  __syncthreads();
  for (int idx = tid; idx < 6400; idx += 512) {
    int c = idx / 100, p = idx % 100;
    int g = n * CTV_ + c * TV_ + t0 * V_ + p;
    float v = lrelu(x[g] + p2[g] * sc[c] + sh[c]);
    yb[c * 101 + p] = v;
    y_b[g] = v;
  }
  __syncthreads();
  for (int idx = tid; idx < 1600; idx += 512) {
    int v = idx >> 6, c = idx & 63;
    const float* yr = yb + c * 101 + v;
    float4 w4 = make_float4(yr[0], yr[25], yr[50], yr[75]);
    *(float4*)(y_bT + n * CTV_ + v * 4096 + c * 64 + t0) = w4;
  }
}

// -------- K4b: qk[n][r(32)][t][v] for temporal subnet s
__global__ __launch_bounds__(512) void k4b_qk(
    const float* __restrict__ y_b, const float* __restrict__ pe_t,
    const float* __restrict__ Win_t, const float* __restrict__ bin_t,
    int s, float* __restrict__ qk) {
  int n = blockIdx.x, t0 = blockIdx.y * 4, tid = threadIdx.x;
  __shared__ alignas(16) float ypeT[100 * 64];  // [p][c-swz]
  __shared__ alignas(16) float wlt[32 * 64];
  for (int idx = tid; idx < 2048; idx += 512) {
    int r = idx >> 6, c = idx & 63;
    int row = (r < IC_) ? (s * IC_ + r) : ((S_ + s) * IC_ + (r - IC_));
    wlt[r * 64 + c] = Win_t[row * C_ + c];
  }
  for (int idx = tid; idx < 6400; idx += 512) {
    int c = idx / 100, p = idx % 100;
    int gg = c * TV_ + t0 * V_ + p;
    ypeT[p * 64 + sw64(p, c >> 2) + (c & 3)] = y_b[n * CTV_ + gg] + pe_t[gg];
  }
  __syncthreads();
  for (int idx = tid; idx < 3200; idx += 512) {
    int r = idx / 100, p = idx % 100;
    int row = (r < IC_) ? (s * IC_ + r) : ((S_ + s) * IC_ + (r - IC_));
    float a = bin_t[row];
#pragma unroll
    for (int cq = 0; cq < 16; ++cq)
      a += dot4(*(const float4*)&wlt[r * 64 + cq * 4],
                *(const float4*)&ypeT[p * 64 + sw64(p, cq)]);
    qk[n * 51200 + r * TV_ + t0 * V_ + p] = a;
  }
}

// -------- K5: temporal attention matrices for subnet s, one block per n
__global__ __launch_bounds__(512) void k5_att_t(
    const float* __restrict__ qk, const float* __restrict__ y_b,
    const float* __restrict__ x1t, const float* __restrict__ alphat,
    const float* __restrict__ betat, const float* __restrict__ att0t,
    int s, float* __restrict__ att_t_out) {
  int n = blockIdx.x, tid = threadIdx.x;
  __shared__ alignas(16) float buf[8 * 2048];  // 8 planes [row(64)][v-swz(32)]
  float acc1[8], acc2[8];
#pragma unroll
  for (int j = 0; j < 8; ++j) { acc1[j] = 0.f; acc2[j] = 0.f; }
  int q = tid & 63, w8 = tid >> 6;
  // ---- QK^T: planes 0..3 = Q(c), 4..7 = K(c)
  for (int cc = 0; cc < 4; ++cc) {
    __syncthreads();
    const float* qb = qk + n * 51200 + (cc * 4) * TV_;
    const float* kb = qk + n * 51200 + (IC_ + cc * 4) * TV_;
    for (int idx = tid; idx < 6400; idx += 512) {
      int c = idx / 1600, r = idx % 1600, t = r / 25, vv = r % 25;
      int a = t * 32 + sw32(t, vv >> 2) + (vv & 3);
      buf[c * 2048 + a] = qb[idx];
      buf[(4 + c) * 2048 + a] = kb[idx];
    }
    __syncthreads();
#pragma unroll
    for (int j = 0; j < 8; ++j) {
      int tt = j * 8 + w8;
      float a = acc1[j];
#pragma unroll
      for (int c = 0; c < 4; ++c) {
        const float* Q = &buf[c * 2048 + tt * 32];
        const float* K = &buf[(4 + c) * 2048 + q * 32];
#pragma unroll
        for (int vq = 0; vq < 6; ++vq)
          a += dot4(*(const float4*)&Q[sw32(tt, vq)], *(const float4*)&K[sw32(q, vq)]);
        a += Q[sw32(tt, 6)] * K[sw32(q, 6)];
      }
      acc1[j] = a;
    }
  }
  // ---- x1 term: planes 0..3 = Y(c), 4..7 = X1(c), 16 chunks of 4 c
  for (int cc = 0; cc < 16; ++cc) {
    __syncthreads();
    const float* yb = y_b + n * CTV_ + cc * 4 * TV_;
    const float* xb = x1t + s * CTV_ + cc * 4 * TV_;
    for (int idx = tid; idx < 6400; idx += 512) {
      int c = idx / 1600, r = idx % 1600, t = r / 25, vv = r % 25;
      int a = t * 32 + sw32(t, vv >> 2) + (vv & 3);
      buf[c * 2048 + a] = yb[idx];
      buf[(4 + c) * 2048 + a] = xb[idx];
    }
    __syncthreads();
#pragma unroll
    for (int j = 0; j < 8; ++j) {
      int tt = j * 8 + w8;
      float a = acc2[j];
#pragma unroll
      for (int c = 0; c < 4; ++c) {
        const float* Y = &buf[c * 2048 + q * 32];
        const float* X = &buf[(4 + c) * 2048 + tt * 32];
#pragma unroll
        for (int vq = 0; vq < 6; ++vq)
          a += dot4(*(const float4*)&Y[sw32(q, vq)], *(const float4*)&X[sw32(tt, vq)]);
        a += Y[sw32(q, 6)] * X[sw32(tt, 6)];
      }
      acc2[j] = a;
    }
  }
  float al = alphat[s], be = betat[s];
#pragma unroll
  for (int j = 0; j < 8; ++j) {
    int out = (j * 8 + w8) * 64 + q;
    float a = tanhf(acc1[j] * (1.f / 400.f)) * al + tanhf(acc2[j]) * be
            + att0t[s * 4096 + out];
    att_t_out[(n * S_ + s) * 4096 + out] = a;
  }
}

// -------- K6: p3T[n][v][o][q] via two register-tiled GEMMs ; partial stats
__global__ __launch_bounds__(512) void k6_p3(
    const float* __restrict__ y_bT, const float* __restrict__ att_t,
    const float* __restrict__ Wout_t, const float* __restrict__ bout_t,
    float* __restrict__ p3T, float* __restrict__ part) {
  int n = blockIdx.x, v = blockIdx.y, tid = threadIdx.x;
  int q = tid & 63, w8 = tid >> 6;
  __shared__ alignas(16) float yl[64 * 68];   // Y[c][t] broadcast rows
  __shared__ alignas(16) float aT[64 * 64];   // A^T [q][t-swz]
  __shared__ alignas(16) float wl[64 * 68];   // W[o][c] broadcast rows
  __shared__ alignas(16) float zsT[64 * 64];  // Z^T [q][c-swz]
  for (int idx = tid; idx < 4096; idx += 512) {
    int c = idx >> 6, t = idx & 63;
    yl[c * 68 + t] = y_bT[n * CTV_ + v * 4096 + idx];
  }
  float acc[8];
#pragma unroll
  for (int j = 0; j < 8; ++j) acc[j] = 0.f;
  for (int s = 0; s < S_; ++s) {
    __syncthreads();
    for (int idx = tid; idx < 4096; idx += 512) {
      int t = idx >> 6, qq = idx & 63;
      aT[qq * 64 + sw64(qq, t >> 2) + (t & 3)] = att_t[(n * S_ + s) * 4096 + idx];
      int oo = idx >> 6, c = idx & 63;
      wl[oo * 68 + c] = Wout_t[oo * 192 + s * 64 + c];
    }
    __syncthreads();
    // GEMM1: Z[c][q] = sum_t Y[c][t]*A[t][q]; thread owns c=w8+8k, col q
    float accz[8];
#pragma unroll
    for (int k = 0; k < 8; ++k) accz[k] = 0.f;
#pragma unroll
    for (int tq = 0; tq < 16; ++tq) {
      float4 a4 = *(const float4*)&aT[q * 64 + sw64(q, tq)];
#pragma unroll
      for (int k = 0; k < 8; ++k)
        accz[k] += dot4(*(const float4*)&yl[(w8 + 8 * k) * 68 + tq * 4], a4);
    }
#pragma unroll
    for (int k = 0; k < 8; ++k) {
      int c = w8 + 8 * k;
      zsT[q * 64 + sw64(q, c >> 2) + (c & 3)] = accz[k];
    }
    __syncthreads();
    // GEMM2: acc[j] += sum_c W[o=w8+8j][c] * Z[c][q]
#pragma unroll
    for (int cq = 0; cq < 16; ++cq) {
      float4 z4 = *(const float4*)&zsT[q * 64 + sw64(q, cq)];
#pragma unroll
      for (int j = 0; j < 8; ++j) {
        float4 w4 = *(const float4*)&wl[(w8 + 8 * j) * 68 + cq * 4];
        acc[j] += dot4(w4, z4);
      }
    }
  }
#pragma unroll
  for (int j = 0; j < 8; ++j) {
    int o = w8 + 8 * j;
    float val = acc[j] + bout_t[o];
    p3T[n * CTV_ + v * 4096 + o * 64 + q] = val;
  }
  // partial stats: wave-reduce per o, plain store (no atomics)
#pragma unroll
  for (int j = 0; j < 8; ++j) {
    int o = w8 + 8 * j;
    float val = acc[j] + bout_t[o];
    float ls = val, lq2 = val * val;
#pragma unroll
    for (int m = 32; m > 0; m >>= 1) { ls += __shfl_xor(ls, m); lq2 += __shfl_xor(lq2, m); }
    if (q == 0) {
      int bid = blockIdx.x * V_ + blockIdx.y;
      part[bid * 128 + o] = ls;
      part[bid * 128 + 64 + o] = lq2;
    }
  }
}

// -------- K7: z_a = lrelu(y_bT + bn3(p3T)); p4T = Wff_t @ z_a + bff_t ; partial stats
__global__ __launch_bounds__(512) void k7_p4(
    const float* __restrict__ y_bT, const float* __restrict__ p3T,
    const float* __restrict__ Wff_t, const float* __restrict__ bff_t,
    const float* __restrict__ bnw3, const float* __restrict__ bnb3,
    const float* __restrict__ stats, float* __restrict__ p4T,
    float* __restrict__ part) {
  int n = blockIdx.x, v = blockIdx.y, tid = threadIdx.x;
  int q = tid & 63, w8 = tid >> 6;
  __shared__ alignas(16) float zaT[64 * 64];  // [t][c-swz]
  __shared__ alignas(16) float wl[64 * 68];   // [o][c] broadcast rows
  __shared__ float sc[64], sh[64];
  if (tid < 64) {
    float m = stats[256 + tid] * (1.f / NTVf);
    float var = stats[320 + tid] * (1.f / NTVf) - m * m;
    float r = rsqrtf(var + EPS);
    float scl = bnw3[tid] * r;
    sc[tid] = scl; sh[tid] = bnb3[tid] - m * scl;
  }
  for (int idx = tid; idx < 4096; idx += 512) {
    int oo = idx >> 6, c = idx & 63;
    wl[oo * 68 + c] = Wff_t[idx];
  }
  __syncthreads();
  for (int idx = tid; idx < 4096; idx += 512) {
    int c = idx >> 6, t = idx & 63;
    int g = n * CTV_ + v * 4096 + idx;
    zaT[t * 64 + sw64(t, c >> 2) + (c & 3)] = lrelu(y_bT[g] + p3T[g] * sc[c] + sh[c]);
  }
  __syncthreads();
  float acc[8];
#pragma unroll
  for (int j = 0; j < 8; ++j) acc[j] = bff_t[w8 + 8 * j];
#pragma unroll
  for (int cq = 0; cq < 16; ++cq) {
    float4 zq = *(const float4*)&zaT[q * 64 + sw64(q, cq)];
#pragma unroll
    for (int j = 0; j < 8; ++j) {
      float4 w4 = *(const float4*)&wl[(w8 + 8 * j) * 68 + cq * 4];
      acc[j] += dot4(w4, zq);
    }
  }
#pragma unroll
  for (int j = 0; j < 8; ++j) {
    int o = w8 + 8 * j;
    float val = acc[j];
    p4T[n * CTV_ + v * 4096 + o * 64 + q] = val;
    float ls = val, lq2 = val * val;
#pragma unroll
    for (int m = 32; m > 0; m >>= 1) { ls += __shfl_xor(ls, m); lq2 += __shfl_xor(lq2, m); }
    if (q == 0) {
      int bid = blockIdx.x * V_ + blockIdx.y;
      part[bid * 128 + o] = ls;
      part[bid * 128 + 64 + o] = lq2;
    }
  }
}

// -------- K8: out = lrelu(y_b + bn4(p4)) with LDS transpose back, in-place
__global__ __launch_bounds__(512) void k8_out(
    const float* __restrict__ p4T, const float* __restrict__ bnw4,
    const float* __restrict__ bnb4, const float* __restrict__ stats,
    float* __restrict__ out) {
  int n = blockIdx.x, ct0 = blockIdx.y * 256, tid = threadIdx.x;
  __shared__ float tile[25 * 257];
  __shared__ float sc[64], sh[64];
  if (tid < 64) {
    float m = stats[384 + tid] * (1.f / NTVf);
    float var = stats[448 + tid] * (1.f / NTVf) - m * m;
    float r = rsqrtf(var + EPS);
    float scl = bnw4[tid] * r;
    sc[tid] = scl; sh[tid] = bnb4[tid] - m * scl;
  }
  for (int idx = tid; idx < 6400; idx += 512) {
    int v = idx >> 8, ctl = idx & 255;
    tile[v * 257 + ctl] = p4T[n * CTV_ + v * 4096 + ct0 + ctl];
  }
  __syncthreads();
  float* base = out + n * CTV_ + ct0 * 25;
  for (int idx = tid; idx < 6400; idx += 512) {
    int ctl = idx / 25, vv = idx % 25;
    int c = (ct0 + ctl) >> 6;
    float val = base[idx] + tile[vv * 257 + ctl] * sc[c] + sh[c];
    base[idx] = lrelu(val);
  }
}

extern "C" void kernel_launch(void* const* d_in, const int* in_sizes, int n_in,
                              void* d_out, int out_size, void* d_ws, size_t ws_size,
                              hipStream_t stream) {
  // setup_inputs() DICT order (pe_t is index 2!)
  const float* x       = (const float*)d_in[0];
  const float* pe_s    = (const float*)d_in[1];
  const float* pe_t    = (const float*)d_in[2];
  const float* Win_s   = (const float*)d_in[3];
  const float* bin_s   = (const float*)d_in[4];
  const float* alphas  = (const float*)d_in[5];
  const float* x1_nets = (const float*)d_in[6];
  const float* betas   = (const float*)d_in[7];
  const float* att0s   = (const float*)d_in[8];
  const float* Wout_s  = (const float*)d_in[9];
  const float* bout_s  = (const float*)d_in[10];
  const float* bnw1    = (const float*)d_in[11];
  const float* bnb1    = (const float*)d_in[12];
  const float* Wff_s   = (const float*)d_in[13];
  const float* bff_s   = (const float*)d_in[14];
  const float* bnw2    = (const float*)d_in[15];
  const float* bnb2    = (const float*)d_in[16];
  const float* Win_t   = (const float*)d_in[17];
  const float* bin_t   = (const float*)d_in[18];
  const float* alphat  = (const float*)d_in[19];
  const float* x1_nett = (const float*)d_in[20];
  const float* betat   = (const float*)d_in[21];
  const float* att0t   = (const float*)d_in[22];
  const float* Wout_t  = (const float*)d_in[23];
  const float* bout_t  = (const float*)d_in[24];
  const float* bnw3    = (const float*)d_in[25];
  const float* bnb3    = (const float*)d_in[26];
  const float* Wff_t   = (const float*)d_in[27];
  const float* bff_t   = (const float*)d_in[28];
  const float* bnw4    = (const float*)d_in[29];
  const float* bnb4    = (const float*)d_in[30];

  if (n_in < 31) return;
  if (in_sizes[0] != N_ * CTV_) return;
  if (in_sizes[2] != CTV_) return;
  if (in_sizes[3] != 2 * S_ * IC_ * C_) return;
  if (in_sizes[6] != S_ * CTV_) return;
  if (in_sizes[9] != C_ * S_ * C_) return;

  float* ws = (float*)d_ws;
  const size_t off_att_s = 0;
  const size_t off_att_t = 480000;               // 3,145,728 floats
  const size_t off_corr  = off_att_t + 3145728;
  const size_t off_stats = off_corr + 1875;
  const size_t off_R1    = 3628160;
  const size_t off_R2    = off_R1 + 26214400;
  const size_t off_R3    = off_R2 + 26214400;
  const size_t need      = (off_R3 + 26214400) * sizeof(float);
  if (ws_size < need) return;

  float* att_s = ws + off_att_s;
  float* att_t = ws + off_att_t;
  float* corr  = ws + off_corr;
  float* stats = ws + off_stats;
  float* R1    = ws + off_R1;   // p1, then qk (13.1M used), then p3T
  float* R2    = ws + off_R2;   // p2, then partB, then p4T
  float* y_bT  = ws + off_R3;
  float* y_b   = (float*)d_out;
  // part buffers aliased into DEAD regions (no ws growth):
  float* partA = att_t;         // stages 0,1 (att_t unwritten until k5) and 3 (dead after k6)
  float* partB = R2;            // stage 2 (p2 dead after k4a; p4T written after kred)

  hipMemsetAsync(corr, 0, 1875 * sizeof(float), stream);
  k0_corr<<<dim3(S_ * V_), 256, 0, stream>>>(x1_nets, pe_s, corr);
  k1_att_s<<<dim3(N_, S_), 512, 0, stream>>>(x, pe_s, Win_s, bin_s, x1_nets,
                                             alphas, betas, att0s, corr, att_s);
  k2_p1<<<dim3(N_, 16), 512, 0, stream>>>(x, att_s, Wout_s, bout_s, R1, partA);
  kred<<<128, 256, 0, stream>>>(partA, 4096, stats + 0);
  k3_p2<<<dim3(N_, 16), 512, 0, stream>>>(x, R1, Wff_s, bff_s, bnw1, bnb1, stats,
                                          R2, partA);
  kred<<<128, 256, 0, stream>>>(partA, 4096, stats + 128);
  k4a_yb<<<dim3(N_, 16), 512, 0, stream>>>(x, R2, bnw2, bnb2, stats, y_b, y_bT);
  for (int s = 0; s < S_; ++s) {
    k4b_qk<<<dim3(N_, 16), 512, 0, stream>>>(y_b, pe_t, Win_t, bin_t, s, R1);
    k5_att_t<<<dim3(N_), 512, 0, stream>>>(R1, y_b, x1_nett, alphat, betat, att0t,
                                           s, att_t);
  }
  k6_p3<<<dim3(N_, V_), 512, 0, stream>>>(y_bT, att_t, Wout_t, bout_t, R1, partB);
  kred<<<128, 256, 0, stream>>>(partB, 6400, stats + 256);
  k7_p4<<<dim3(N_, V_), 512, 0, stream>>>(y_bT, R1, Wff_t, bff_t, bnw3, bnb3, stats,
                                          R2, partA);
  kred<<<128, 256, 0, stream>>>(partA, 6400, stats + 384);
  k8_out<<<dim3(N_, 16), 512, 0, stream>>>(R2, bnw4, bnb4, stats, y_b);
}

// Round 8
// 4737.706 us; speedup vs baseline: 2.4160x; 1.4394x over previous
//
#include <hip/hip_runtime.h>

#define N_   256
#define C_   64
#define T_   64
#define V_   25
#define S_   3
#define IC_  16
#define TV_  1600
#define CTV_ 102400
#define NTVf 409600.0f
#define EPS  1e-5f

__device__ __forceinline__ float lrelu(float v) { return v >= 0.f ? v : 0.1f * v; }
__device__ __forceinline__ float dot4(float4 a, float4 b) {
  return a.x * b.x + a.y * b.y + a.z * b.z + a.w * b.w;
}
// swizzled slot offsets: row stride 64 floats (16 quads) / 32 floats (8 quads)
__device__ __forceinline__ int sw64(int row, int q) { return (q ^ (row & 15)) << 2; }
__device__ __forceinline__ int sw32(int row, int q) { return (q ^ (row & 7)) << 2; }

// -------- kred: stats[ch] = sum_i part[i*128 + ch], ch in [0,128)
__global__ __launch_bounds__(256) void kred(const float* __restrict__ part, int nblk,
                                            float* __restrict__ out) {
  int ch = blockIdx.x;
  float a = 0.f;
  for (int i = threadIdx.x; i < nblk; i += 256) a += part[i * 128 + ch];
  __shared__ float red[4];
#pragma unroll
  for (int off = 32; off > 0; off >>= 1) a += __shfl_down(a, off);
  if ((threadIdx.x & 63) == 0) red[threadIdx.x >> 6] = a;
  __syncthreads();
  if (threadIdx.x == 0) out[ch] = red[0] + red[1] + red[2] + red[3];
}

// -------- K0: corr[s,u,v] = sum_{c,t} x1_nets[s,c,t,u] * pe_s[c,t,v]
__global__ __launch_bounds__(256) void k0_corr(const float* __restrict__ x1s,
                                               const float* __restrict__ pe_s,
                                               float* __restrict__ corr) {
  int b = blockIdx.x; int s = b / V_, u = b % V_;
  float acc[V_];
#pragma unroll
  for (int v = 0; v < V_; ++v) acc[v] = 0.f;
  for (int idx = threadIdx.x; idx < C_ * T_; idx += 256) {
    float xv = x1s[(s * C_ * T_ + idx) * V_ + u];
    const float* per = pe_s + idx * V_;
#pragma unroll
    for (int v = 0; v < V_; ++v) acc[v] += xv * per[v];
  }
#pragma unroll
  for (int v = 0; v < V_; ++v) {
    float a = acc[v];
#pragma unroll
    for (int off = 32; off > 0; off >>= 1) a += __shfl_down(a, off);
    if ((threadIdx.x & 63) == 0) atomicAdd(&corr[(s * V_ + u) * V_ + v], a);
  }
}

// -------- K1 (REWRITE): spatial attention, one block per (n,s).
// Register-tiled 4x4-per-lane GEMMs with wave-level K split + LDS reduction.
__global__ __launch_bounds__(512) void k1_att_s(
    const float* __restrict__ x, const float* __restrict__ pe_s,
    const float* __restrict__ Win_s, const float* __restrict__ bin_s,
    const float* __restrict__ x1s, const float* __restrict__ alphas,
    const float* __restrict__ betas, const float* __restrict__ att0s,
    const float* __restrict__ corr, float* __restrict__ att_s_out) {
  int n = blockIdx.x, s = blockIdx.y, tid = threadIdx.x;
  int wave = tid >> 6, lane = tid & 63, li = lane >> 3, lj = lane & 7;
  __shared__ float wls[2048];                 // Win rows [r(32)][c(64)]
  __shared__ alignas(16) float xpeO[6400];    // [p][c-swz] for qk GEMM
  __shared__ alignas(16) float xq[2176];      // q-tile [u(32)][k(64)+pad4] k=ic*4+dt
  __shared__ alignas(16) float xk[2176];      // k-tile [v(32)][k]
  __shared__ alignas(16) float xAB[16640];    // xA=[u][k(256)+4] x1 ; xB same for xpe
  float* xA = xAB;
  float* xB = xAB + 8320;
  for (int idx = tid; idx < 2048; idx += 512) {
    int r = idx >> 6, c = idx & 63;
    int row = (r < IC_) ? (s * IC_ + r) : ((S_ + s) * IC_ + (r - IC_));
    wls[r * 64 + c] = Win_s[row * C_ + c];
  }
  // zero pad rows 25..31 (stay zero: staging only writes rows < 25)
  for (int idx = tid; idx < 7 * 260; idx += 512) {
    xA[25 * 260 + idx] = 0.f; xB[25 * 260 + idx] = 0.f;
  }
  for (int idx = tid; idx < 7 * 68; idx += 512) {
    xq[25 * 68 + idx] = 0.f; xk[25 * 68 + idx] = 0.f;
  }
  __syncthreads();
  // qk phase mapping: fixed row per thread, 16 threads share a row over p
  int qr = tid >> 4, qpp = tid & 15;
  int qrow = (qr < IC_) ? (s * IC_ + qr) : ((S_ + s) * IC_ + (qr - IC_));
  float qbias = bin_s[qrow];
  float4 wreg[16];
#pragma unroll
  for (int cq = 0; cq < 16; ++cq) wreg[cq] = *(const float4*)&wls[qr * 64 + cq * 4];
  float* qdst = (qr < IC_) ? xq : xk;
  int qrr = qr & 15;

  float a1acc[16], a2acc[16];
#pragma unroll
  for (int i = 0; i < 16; ++i) { a1acc[i] = 0.f; a2acc[i] = 0.f; }

  for (int t0 = 0; t0 < T_; t0 += 4) {
    __syncthreads();
    for (int idx = tid; idx < 6400; idx += 512) {
      int c = idx / 100, p = idx % 100, dt = p / 25, u = p % 25;
      int g = c * TV_ + t0 * V_ + p;
      float xpe = x[n * CTV_ + g] + pe_s[g];
      int k = c * 4 + dt;
      xB[u * 260 + k] = xpe;
      xA[u * 260 + k] = x1s[s * CTV_ + g];
      xpeO[p * 64 + sw64(p, c >> 2) + (c & 3)] = xpe;
    }
    __syncthreads();
    // qk: q/k rows into [u][ic*4+dt] layout
    for (int p = qpp; p < 100; p += 16) {
      float a = qbias;
#pragma unroll
      for (int cq = 0; cq < 16; ++cq)
        a += dot4(wreg[cq], *(const float4*)&xpeO[p * 64 + sw64(p, cq)]);
      int dt = p / 25, u = p % 25;
      qdst[u * 68 + qrr * 4 + dt] = a;
    }
    __syncthreads();
    // a2: K=256 split 8 waves x 8 quads
#pragma unroll
    for (int q8 = 0; q8 < 8; ++q8) {
      int kb = (wave * 8 + q8) * 4;
      float4 av[4], bv[4];
#pragma unroll
      for (int a = 0; a < 4; ++a) av[a] = *(const float4*)&xA[(li + 8 * a) * 260 + kb];
#pragma unroll
      for (int b = 0; b < 4; ++b) bv[b] = *(const float4*)&xB[(lj + 8 * b) * 260 + kb];
#pragma unroll
      for (int a = 0; a < 4; ++a)
#pragma unroll
        for (int b = 0; b < 4; ++b) a2acc[a * 4 + b] += dot4(av[a], bv[b]);
    }
    // a1: K=64 split 8 waves x 2 quads
#pragma unroll
    for (int q2 = 0; q2 < 2; ++q2) {
      int kb = (wave * 2 + q2) * 4;
      float4 av[4], bv[4];
#pragma unroll
      for (int a = 0; a < 4; ++a) av[a] = *(const float4*)&xq[(li + 8 * a) * 68 + kb];
#pragma unroll
      for (int b = 0; b < 4; ++b) bv[b] = *(const float4*)&xk[(lj + 8 * b) * 68 + kb];
#pragma unroll
      for (int a = 0; a < 4; ++a)
#pragma unroll
        for (int b = 0; b < 4; ++b) a1acc[a * 4 + b] += dot4(av[a], bv[b]);
    }
  }
  // cross-wave reduction (reuse xAB; stride 33 to dodge write conflicts)
  __syncthreads();
#pragma unroll
  for (int a = 0; a < 4; ++a)
#pragma unroll
    for (int b = 0; b < 4; ++b)
      xAB[wave * 1056 + (li + 8 * a) * 33 + (lj + 8 * b)] = a2acc[a * 4 + b];
  __syncthreads();
  float a2sum[2] = {0.f, 0.f};
#pragma unroll
  for (int k = 0; k < 2; ++k) {
    int o = tid + k * 512;
    if (o < 625) {
      int u = o / 25, v = o % 25;
      float sm = 0.f;
#pragma unroll
      for (int w = 0; w < 8; ++w) sm += xAB[w * 1056 + u * 33 + v];
      a2sum[k] = sm;
    }
  }
  __syncthreads();
#pragma unroll
  for (int a = 0; a < 4; ++a)
#pragma unroll
    for (int b = 0; b < 4; ++b)
      xAB[wave * 1056 + (li + 8 * a) * 33 + (lj + 8 * b)] = a1acc[a * 4 + b];
  __syncthreads();
  float al = alphas[s], be = betas[s];
#pragma unroll
  for (int k = 0; k < 2; ++k) {
    int o = tid + k * 512;
    if (o < 625) {
      int u = o / 25, v = o % 25;
      float sm = 0.f;
#pragma unroll
      for (int w = 0; w < 8; ++w) sm += xAB[w * 1056 + u * 33 + v];
      float a = tanhf(sm * (1.f / 1024.f)) * al
              + tanhf(a2sum[k] - corr[s * 625 + o]) * be
              + att0s[s * 625 + o];
      att_s_out[(n * S_ + s) * 625 + o] = a;
    }
  }
}

// -------- K2: p1 = Wout_s @ (x (x) att_s) + bout_s ; partial stats
__global__ __launch_bounds__(512) void k2_p1(
    const float* __restrict__ x, const float* __restrict__ att_s,
    const float* __restrict__ Wout_s, const float* __restrict__ bout_s,
    float* __restrict__ p1, float* __restrict__ part) {
  int n = blockIdx.x, t0 = blockIdx.y * 4, tid = threadIdx.x;
  __shared__ alignas(16) float xc2[64 * 112];   // [c][t*28+u] broadcast rows
  __shared__ alignas(16) float attT[25 * 32];   // [v][u-swz]
  __shared__ alignas(16) float xaT[100 * 68];   // [p][c]
  __shared__ alignas(16) float wl[64 * 68];     // [o][c]
  for (int idx = tid; idx < 6400; idx += 512) {
    int c = idx / 100, p = idx % 100, t = p / 25, u = p % 25;
    xc2[c * 112 + t * 28 + u] = x[n * CTV_ + c * TV_ + t0 * V_ + p];
  }
  int o = tid >> 3, pb = tid & 7;
  float acc[13];
#pragma unroll
  for (int j = 0; j < 13; ++j) acc[j] = 0.f;
  for (int s = 0; s < S_; ++s) {
    __syncthreads();
    for (int idx = tid; idx < 625; idx += 512) {
      int u = idx / 25, vv = idx % 25;
      attT[vv * 32 + sw32(vv, u >> 2) + (u & 3)] = att_s[n * 1875 + s * 625 + idx];
    }
    for (int idx = tid; idx < 4096; idx += 512) {
      int oo = idx >> 6, c = idx & 63;
      wl[oo * 68 + c] = Wout_s[oo * (S_ * C_) + s * C_ + c];
    }
    __syncthreads();
    for (int idx = tid; idx < 6400; idx += 512) {
      int c = idx / 100, p = idx % 100, t = p / 25, v = p % 25;
      const float* xr = &xc2[c * 112 + t * 28];
      const float* ar = &attT[v * 32];
      float a = 0.f;
#pragma unroll
      for (int uq = 0; uq < 6; ++uq)
        a += dot4(*(const float4*)&xr[uq * 4], *(const float4*)&ar[sw32(v, uq)]);
      a += xr[24] * ar[sw32(v, 6)];
      xaT[p * 68 + c] = a;
    }
    __syncthreads();
#pragma unroll
    for (int cq = 0; cq < 16; ++cq) {
      float4 w4 = *(const float4*)&wl[o * 68 + cq * 4];
#pragma unroll
      for (int j = 0; j < 13; ++j) {
        int p = pb + 8 * j;
        if (p < 100)
          acc[j] += dot4(w4, *(const float4*)&xaT[p * 68 + cq * 4]);
      }
    }
  }
  float b = bout_s[o], lsum = 0.f, lsq = 0.f;
  float* prow = p1 + n * CTV_ + o * TV_ + t0 * V_;
#pragma unroll
  for (int j = 0; j < 13; ++j) {
    int p = pb + 8 * j;
    if (p < 100) {
      float v = acc[j] + b;
      prow[p] = v;
      lsum += v; lsq += v * v;
    }
  }
  lsum += __shfl_down(lsum, 4); lsum += __shfl_down(lsum, 2); lsum += __shfl_down(lsum, 1);
  lsq  += __shfl_down(lsq, 4);  lsq  += __shfl_down(lsq, 2);  lsq  += __shfl_down(lsq, 1);
  if (pb == 0) {
    int bid = blockIdx.x * 16 + blockIdx.y;
    part[bid * 128 + o] = lsum;
    part[bid * 128 + 64 + o] = lsq;
  }
}

// -------- K3: y_a = lrelu(x + bn1(p1)); p2 = Wff_s @ y_a + bff_s; partial stats
__global__ __launch_bounds__(512) void k3_p2(
    const float* __restrict__ x, const float* __restrict__ p1,
    const float* __restrict__ Wff_s, const float* __restrict__ bff_s,
    const float* __restrict__ bnw1, const float* __restrict__ bnb1,
    const float* __restrict__ stats, float* __restrict__ p2,
    float* __restrict__ part) {
  int n = blockIdx.x, t0 = blockIdx.y * 4, tid = threadIdx.x;
  __shared__ alignas(16) float yaT[100 * 68];
  __shared__ alignas(16) float wl[64 * 68];
  __shared__ float sc[64], sh[64];
  if (tid < 64) {
    float m = stats[tid] * (1.f / NTVf);
    float var = stats[64 + tid] * (1.f / NTVf) - m * m;
    float r = rsqrtf(var + EPS);
    float scl = bnw1[tid] * r;
    sc[tid] = scl; sh[tid] = bnb1[tid] - m * scl;
  }
  for (int idx = tid; idx < 4096; idx += 512) {
    int oo = idx >> 6, c = idx & 63;
    wl[oo * 68 + c] = Wff_s[idx];
  }
  __syncthreads();
  for (int idx = tid; idx < 6400; idx += 512) {
    int c = idx / 100, p = idx % 100;
    int g = n * CTV_ + c * TV_ + t0 * V_ + p;
    yaT[p * 68 + c] = lrelu(x[g] + p1[g] * sc[c] + sh[c]);
  }
  __syncthreads();
  int o = tid >> 3, pb = tid & 7;
  float acc[13];
#pragma unroll
  for (int j = 0; j < 13; ++j) acc[j] = 0.f;
#pragma unroll
  for (int cq = 0; cq < 16; ++cq) {
    float4 w4 = *(const float4*)&wl[o * 68 + cq * 4];
#pragma unroll
    for (int j = 0; j < 13; ++j) {
      int p = pb + 8 * j;
      if (p < 100)
        acc[j] += dot4(w4, *(const float4*)&yaT[p * 68 + cq * 4]);
    }
  }
  float b = bff_s[o], lsum = 0.f, lsq = 0.f;
  float* prow = p2 + n * CTV_ + o * TV_ + t0 * V_;
#pragma unroll
  for (int j = 0; j < 13; ++j) {
    int p = pb + 8 * j;
    if (p < 100) {
      float v = acc[j] + b;
      prow[p] = v;
      lsum += v; lsq += v * v;
    }
  }
  lsum += __shfl_down(lsum, 4); lsum += __shfl_down(lsum, 2); lsum += __shfl_down(lsum, 1);
  lsq  += __shfl_down(lsq, 4);  lsq  += __shfl_down(lsq, 2);  lsq  += __shfl_down(lsq, 1);
  if (pb == 0) {
    int bid = blockIdx.x * 16 + blockIdx.y;
    part[bid * 128 + o] = lsum;
    part[bid * 128 + 64 + o] = lsq;
  }
}

// -------- K4a: y_b = lrelu(x + bn2(p2)) -> d_out (y_b) and transposed y_bT
__global__ __launch_bounds__(512) void k4a_yb(
    const float* __restrict__ x, const float* __restrict__ p2,
    const float* __restrict__ bnw2, const float* __restrict__ bnb2,
    const float* __restrict__ stats,
    float* __restrict__ y_b, float* __restrict__ y_bT) {
  int n = blockIdx.x, t0 = blockIdx.y * 4, tid = threadIdx.x;
  __shared__ float yb[64 * 101];
  __shared__ float sc[64], sh[64];
  if (tid < 64) {
    float m = stats[128 + tid] * (1.f / NTVf);
    float var = stats[192 + tid] * (1.f / NTVf) - m * m;
    float r = rsqrtf(var + EPS);
    float scl = bnw2[tid] * r;
    sc[tid] = scl; sh[tid] = bnb2[tid] - m * scl;
  }
  __syncthreads();
  for (int idx = tid; idx < 6400; idx += 512) {
    int c = idx / 100, p = idx % 100;
    int g = n * CTV_ + c * TV_ + t0 * V_ + p;
    float v = lrelu(x[g] + p2[g] * sc[c] + sh[c]);
    yb[c * 101 + p] = v;
    y_b[g] = v;
  }
  __syncthreads();
  for (int idx = tid; idx < 1600; idx += 512) {
    int v = idx >> 6, c = idx & 63;
    const float* yr = yb + c * 101 + v;
    float4 w4 = make_float4(yr[0], yr[25], yr[50], yr[75]);
    *(float4*)(y_bT + n * CTV_ + v * 4096 + c * 64 + t0) = w4;
  }
}

// -------- K4b (FOLDED): qk_all[n][r(96)][t][v], all 3 subnets in one pass
__global__ __launch_bounds__(512) void k4b_qk(
    const float* __restrict__ y_b, const float* __restrict__ pe_t,
    const float* __restrict__ Win_t, const float* __restrict__ bin_t,
    float* __restrict__ qk_all) {
  int n = blockIdx.x, t0 = blockIdx.y * 4, tid = threadIdx.x;
  __shared__ alignas(16) float ypeT[6400];  // [p][c-swz]
  __shared__ alignas(16) float wlt[6144];   // [r(96)][c]
  for (int idx = tid; idx < 6144; idx += 512) wlt[idx] = Win_t[idx];
  for (int idx = tid; idx < 6400; idx += 512) {
    int c = idx / 100, p = idx % 100;
    int gg = c * TV_ + t0 * V_ + p;
    ypeT[p * 64 + sw64(p, c >> 2) + (c & 3)] = y_b[n * CTV_ + gg] + pe_t[gg];
  }
  __syncthreads();
  for (int idx = tid; idx < 9600; idx += 512) {
    int r = idx / 100, p = idx % 100;
    float a = bin_t[r];
#pragma unroll
    for (int cq = 0; cq < 16; ++cq)
      a += dot4(*(const float4*)&wlt[r * 64 + cq * 4],
                *(const float4*)&ypeT[p * 64 + sw64(p, cq)]);
    qk_all[n * 153600 + r * TV_ + t0 * V_ + p] = a;
  }
}

// -------- K5 (REWRITE): temporal attention, one block per (n,s).
// 4x4-per-lane register tiling, 2-way K-split across wave pairs.
__global__ __launch_bounds__(512) void k5_att_t(
    const float* __restrict__ qk_all, const float* __restrict__ y_b,
    const float* __restrict__ x1t, const float* __restrict__ alphat,
    const float* __restrict__ betat, const float* __restrict__ att0t,
    float* __restrict__ att_t_out) {
  int n = blockIdx.x, s = blockIdx.y, tid = threadIdx.x;
  int wave = tid >> 6, lane = tid & 63, li = lane >> 3, lj = lane & 7;
  int wq = wave & 1, wt = (wave >> 1) & 1, kh = wave >> 2;
  int tb = wt * 32 + li, qb = wq * 32 + lj;
  __shared__ alignas(16) float A[6400], B[6400];  // [row(64)][k(100)]
  float acc1[16], acc2[16];
#pragma unroll
  for (int i = 0; i < 16; ++i) { acc1[i] = 0.f; acc2[i] = 0.f; }
  // phase 1: acc1[t][q] = sum_{ic,v} q[ic,t,v]*k[ic,q,v]; 4 chunks of 4 ic
  for (int ch = 0; ch < 4; ++ch) {
    __syncthreads();
    const float* qs = qk_all + n * 153600 + (s * IC_ + ch * 4) * TV_;
    const float* ks = qk_all + n * 153600 + (S_ * IC_ + s * IC_ + ch * 4) * TV_;
    for (int idx = tid; idx < 6400; idx += 512) {
      int cp = idx / 1600, rem = idx % 1600, t = rem / 25, v = rem % 25;
      int a = t * 100 + cp * 25 + v;
      A[a] = qs[idx];
      B[a] = ks[idx];
    }
    __syncthreads();
    int lo = kh ? 12 : 0, hi = kh ? 25 : 12;
    for (int qd = lo; qd < hi; ++qd) {
      int kb = qd * 4;
      float4 av[4], bv[4];
#pragma unroll
      for (int a = 0; a < 4; ++a) av[a] = *(const float4*)&A[(tb + 8 * a) * 100 + kb];
#pragma unroll
      for (int b = 0; b < 4; ++b) bv[b] = *(const float4*)&B[(qb + 8 * b) * 100 + kb];
#pragma unroll
      for (int a = 0; a < 4; ++a)
#pragma unroll
        for (int b = 0; b < 4; ++b) acc1[a * 4 + b] += dot4(av[a], bv[b]);
    }
  }
  // phase 2: acc2[t][q] = sum_{c,v} x1t[s,c,t,v]*y[n,c,q,v]; 16 chunks of 4 c
  for (int ch = 0; ch < 16; ++ch) {
    __syncthreads();
    const float* as = x1t + s * CTV_ + ch * 4 * TV_;
    const float* bs = y_b + n * CTV_ + ch * 4 * TV_;
    for (int idx = tid; idx < 6400; idx += 512) {
      int cp = idx / 1600, rem = idx % 1600, t = rem / 25, v = rem % 25;
      int a = t * 100 + cp * 25 + v;
      A[a] = as[idx];
      B[a] = bs[idx];
    }
    __syncthreads();
    int lo = kh ? 12 : 0, hi = kh ? 25 : 12;
    for (int qd = lo; qd < hi; ++qd) {
      int kb = qd * 4;
      float4 av[4], bv[4];
#pragma unroll
      for (int a = 0; a < 4; ++a) av[a] = *(const float4*)&A[(tb + 8 * a) * 100 + kb];
#pragma unroll
      for (int b = 0; b < 4; ++b) bv[b] = *(const float4*)&B[(qb + 8 * b) * 100 + kb];
#pragma unroll
      for (int a = 0; a < 4; ++a)
#pragma unroll
        for (int b = 0; b < 4; ++b) acc2[a * 4 + b] += dot4(av[a], bv[b]);
    }
  }
  // K-half reduction: waves 4..7 -> LDS (stride 33), waves 0..3 combine + finalize
  __syncthreads();
  if (kh) {
#pragma unroll
    for (int a = 0; a < 4; ++a)
#pragma unroll
      for (int b = 0; b < 4; ++b)
        A[(wave - 4) * 1056 + (li + 8 * a) * 33 + (lj + 8 * b)] = acc2[a * 4 + b];
  }
  __syncthreads();
  if (!kh) {
#pragma unroll
    for (int a = 0; a < 4; ++a)
#pragma unroll
      for (int b = 0; b < 4; ++b)
        acc2[a * 4 + b] += A[wave * 1056 + (li + 8 * a) * 33 + (lj + 8 * b)];
  }
  __syncthreads();
  if (kh) {
#pragma unroll
    for (int a = 0; a < 4; ++a)
#pragma unroll
      for (int b = 0; b < 4; ++b)
        A[(wave - 4) * 1056 + (li + 8 * a) * 33 + (lj + 8 * b)] = acc1[a * 4 + b];
  }
  __syncthreads();
  if (!kh) {
    float al = alphat[s], be = betat[s];
#pragma unroll
    for (int a = 0; a < 4; ++a)
#pragma unroll
      for (int b = 0; b < 4; ++b) {
        float a1 = acc1[a * 4 + b] + A[wave * 1056 + (li + 8 * a) * 33 + (lj + 8 * b)];
        int t = tb + 8 * a, q = qb + 8 * b;
        int o = t * 64 + q;
        float val = tanhf(a1 * (1.f / 400.f)) * al + tanhf(acc2[a * 4 + b]) * be
                  + att0t[s * 4096 + o];
        att_t_out[(n * S_ + s) * 4096 + o] = val;
      }
  }
}

// -------- K6: p3T[n][v][o][q] via two register-tiled GEMMs ; partial stats
__global__ __launch_bounds__(512) void k6_p3(
    const float* __restrict__ y_bT, const float* __restrict__ att_t,
    const float* __restrict__ Wout_t, const float* __restrict__ bout_t,
    float* __restrict__ p3T, float* __restrict__ part) {
  int n = blockIdx.x, v = blockIdx.y, tid = threadIdx.x;
  int q = tid & 63, w8 = tid >> 6;
  __shared__ alignas(16) float yl[64 * 68];   // Y[c][t] broadcast rows
  __shared__ alignas(16) float aT[64 * 64];   // A^T [q][t-swz]
  __shared__ alignas(16) float wl[64 * 68];   // W[o][c] broadcast rows
  __shared__ alignas(16) float zsT[64 * 64];  // Z^T [q][c-swz]
  for (int idx = tid; idx < 4096; idx += 512) {
    int c = idx >> 6, t = idx & 63;
    yl[c * 68 + t] = y_bT[n * CTV_ + v * 4096 + idx];
  }
  float acc[8];
#pragma unroll
  for (int j = 0; j < 8; ++j) acc[j] = 0.f;
  for (int s = 0; s < S_; ++s) {
    __syncthreads();
    for (int idx = tid; idx < 4096; idx += 512) {
      int t = idx >> 6, qq = idx & 63;
      aT[qq * 64 + sw64(qq, t >> 2) + (t & 3)] = att_t[(n * S_ + s) * 4096 + idx];
      int oo = idx >> 6, c = idx & 63;
      wl[oo * 68 + c] = Wout_t[oo * 192 + s * 64 + c];
    }
    __syncthreads();
    float accz[8];
#pragma unroll
    for (int k = 0; k < 8; ++k) accz[k] = 0.f;
#pragma unroll
    for (int tq = 0; tq < 16; ++tq) {
      float4 a4 = *(const float4*)&aT[q * 64 + sw64(q, tq)];
#pragma unroll
      for (int k = 0; k < 8; ++k)
        accz[k] += dot4(*(const float4*)&yl[(w8 + 8 * k) * 68 + tq * 4], a4);
    }
#pragma unroll
    for (int k = 0; k < 8; ++k) {
      int c = w8 + 8 * k;
      zsT[q * 64 + sw64(q, c >> 2) + (c & 3)] = accz[k];
    }
    __syncthreads();
#pragma unroll
    for (int cq = 0; cq < 16; ++cq) {
      float4 z4 = *(const float4*)&zsT[q * 64 + sw64(q, cq)];
#pragma unroll
      for (int j = 0; j < 8; ++j) {
        float4 w4 = *(const float4*)&wl[(w8 + 8 * j) * 68 + cq * 4];
        acc[j] += dot4(w4, z4);
      }
    }
  }
#pragma unroll
  for (int j = 0; j < 8; ++j) {
    int o = w8 + 8 * j;
    float val = acc[j] + bout_t[o];
    p3T[n * CTV_ + v * 4096 + o * 64 + q] = val;
    float ls = val, lq2 = val * val;
#pragma unroll
    for (int m = 32; m > 0; m >>= 1) { ls += __shfl_xor(ls, m); lq2 += __shfl_xor(lq2, m); }
    if (q == 0) {
      int bid = blockIdx.x * V_ + blockIdx.y;
      part[bid * 128 + o] = ls;
      part[bid * 128 + 64 + o] = lq2;
    }
  }
}

// -------- K7: z_a = lrelu(y_bT + bn3(p3T)); p4T = Wff_t @ z_a + bff_t ; partial stats
__global__ __launch_bounds__(512) void k7_p4(
    const float* __restrict__ y_bT, const float* __restrict__ p3T,
    const float* __restrict__ Wff_t, const float* __restrict__ bff_t,
    const float* __restrict__ bnw3, const float* __restrict__ bnb3,
    const float* __restrict__ stats, float* __restrict__ p4T,
    float* __restrict__ part) {
  int n = blockIdx.x, v = blockIdx.y, tid = threadIdx.x;
  int q = tid & 63, w8 = tid >> 6;
  __shared__ alignas(16) float zaT[64 * 64];  // [t][c-swz]
  __shared__ alignas(16) float wl[64 * 68];   // [o][c] broadcast rows
  __shared__ float sc[64], sh[64];
  if (tid < 64) {
    float m = stats[256 + tid] * (1.f / NTVf);
    float var = stats[320 + tid] * (1.f / NTVf) - m * m;
    float r = rsqrtf(var + EPS);
    float scl = bnw3[tid] * r;
    sc[tid] = scl; sh[tid] = bnb3[tid] - m * scl;
  }
  for (int idx = tid; idx < 4096; idx += 512) {
    int oo = idx >> 6, c = idx & 63;
    wl[oo * 68 + c] = Wff_t[idx];
  }
  __syncthreads();
  for (int idx = tid; idx < 4096; idx += 512) {
    int c = idx >> 6, t = idx & 63;
    int g = n * CTV_ + v * 4096 + idx;
    zaT[t * 64 + sw64(t, c >> 2) + (c & 3)] = lrelu(y_bT[g] + p3T[g] * sc[c] + sh[c]);
  }
  __syncthreads();
  float acc[8];
#pragma unroll
  for (int j = 0; j < 8; ++j) acc[j] = bff_t[w8 + 8 * j];
#pragma unroll
  for (int cq = 0; cq < 16; ++cq) {
    float4 zq = *(const float4*)&zaT[q * 64 + sw64(q, cq)];
#pragma unroll
    for (int j = 0; j < 8; ++j) {
      float4 w4 = *(const float4*)&wl[(w8 + 8 * j) * 68 + cq * 4];
      acc[j] += dot4(w4, zq);
    }
  }
#pragma unroll
  for (int j = 0; j < 8; ++j) {
    int o = w8 + 8 * j;
    float val = acc[j];
    p4T[n * CTV_ + v * 4096 + o * 64 + q] = val;
    float ls = val, lq2 = val * val;
#pragma unroll
    for (int m = 32; m > 0; m >>= 1) { ls += __shfl_xor(ls, m); lq2 += __shfl_xor(lq2, m); }
    if (q == 0) {
      int bid = blockIdx.x * V_ + blockIdx.y;
      part[bid * 128 + o] = ls;
      part[bid * 128 + 64 + o] = lq2;
    }
  }
}

// -------- K8: out = lrelu(y_b + bn4(p4)) with LDS transpose back, in-place
__global__ __launch_bounds__(512) void k8_out(
    const float* __restrict__ p4T, const float* __restrict__ bnw4,
    const float* __restrict__ bnb4, const float* __restrict__ stats,
    float* __restrict__ out) {
  int n = blockIdx.x, ct0 = blockIdx.y * 256, tid = threadIdx.x;
  __shared__ float tile[25 * 257];
  __shared__ float sc[64], sh[64];
  if (tid < 64) {
    float m = stats[384 + tid] * (1.f / NTVf);
    float var = stats[448 + tid] * (1.f / NTVf) - m * m;
    float r = rsqrtf(var + EPS);
    float scl = bnw4[tid] * r;
    sc[tid] = scl; sh[tid] = bnb4[tid] - m * scl;
  }
  for (int idx = tid; idx < 6400; idx += 512) {
    int v = idx >> 8, ctl = idx & 255;
    tile[v * 257 + ctl] = p4T[n * CTV_ + v * 4096 + ct0 + ctl];
  }
  __syncthreads();
  float* base = out + n * CTV_ + ct0 * 25;
  for (int idx = tid; idx < 6400; idx += 512) {
    int ctl = idx / 25, vv = idx % 25;
    int c = (ct0 + ctl) >> 6;
    float val = base[idx] + tile[vv * 257 + ctl] * sc[c] + sh[c];
    base[idx] = lrelu(val);
  }
}

extern "C" void kernel_launch(void* const* d_in, const int* in_sizes, int n_in,
                              void* d_out, int out_size, void* d_ws, size_t ws_size,
                              hipStream_t stream) {
  // setup_inputs() DICT order (pe_t is index 2!)
  const float* x       = (const float*)d_in[0];
  const float* pe_s    = (const float*)d_in[1];
  const float* pe_t    = (const float*)d_in[2];
  const float* Win_s   = (const float*)d_in[3];
  const float* bin_s   = (const float*)d_in[4];
  const float* alphas  = (const float*)d_in[5];
  const float* x1_nets = (const float*)d_in[6];
  const float* betas   = (const float*)d_in[7];
  const float* att0s   = (const float*)d_in[8];
  const float* Wout_s  = (const float*)d_in[9];
  const float* bout_s  = (const float*)d_in[10];
  const float* bnw1    = (const float*)d_in[11];
  const float* bnb1    = (const float*)d_in[12];
  const float* Wff_s   = (const float*)d_in[13];
  const float* bff_s   = (const float*)d_in[14];
  const float* bnw2    = (const float*)d_in[15];
  const float* bnb2    = (const float*)d_in[16];
  const float* Win_t   = (const float*)d_in[17];
  const float* bin_t   = (const float*)d_in[18];
  const float* alphat  = (const float*)d_in[19];
  const float* x1_nett = (const float*)d_in[20];
  const float* betat   = (const float*)d_in[21];
  const float* att0t   = (const float*)d_in[22];
  const float* Wout_t  = (const float*)d_in[23];
  const float* bout_t  = (const float*)d_in[24];
  const float* bnw3    = (const float*)d_in[25];
  const float* bnb3    = (const float*)d_in[26];
  const float* Wff_t   = (const float*)d_in[27];
  const float* bff_t   = (const float*)d_in[28];
  const float* bnw4    = (const float*)d_in[29];
  const float* bnb4    = (const float*)d_in[30];

  if (n_in < 31) return;
  if (in_sizes[0] != N_ * CTV_) return;
  if (in_sizes[2] != CTV_) return;
  if (in_sizes[3] != 2 * S_ * IC_ * C_) return;
  if (in_sizes[6] != S_ * CTV_) return;
  if (in_sizes[9] != C_ * S_ * C_) return;

  float* ws = (float*)d_ws;
  const size_t off_att_s = 0;
  const size_t off_att_t = 480000;               // 3,145,728 floats
  const size_t off_corr  = off_att_t + 3145728;
  const size_t off_stats = off_corr + 1875;
  const size_t off_R1    = 3628160;
  const size_t off_R2    = off_R1 + 26214400;
  const size_t off_R3    = off_R2 + 26214400;
  const size_t need      = (off_R3 + 26214400) * sizeof(float);
  if (ws_size < need) return;

  float* att_s = ws + off_att_s;
  float* att_t = ws + off_att_t;
  float* corr  = ws + off_corr;
  float* stats = ws + off_stats;
  float* R1    = ws + off_R1;   // p1, then qk_all (spans R1+13.1M of R2), then p3T
  float* R2    = ws + off_R2;   // p2, then tail of qk_all / partB, then p4T
  float* y_bT  = ws + off_R3;
  float* y_b   = (float*)d_out;
  float* partA = att_t;         // stats stages 0,1 (att_t unwritten) and 3 (att_t dead)
  float* partB = R2;            // stats stage 2 (qk_all tail dead after k5)

  hipMemsetAsync(corr, 0, 1875 * sizeof(float), stream);
  k0_corr<<<dim3(S_ * V_), 256, 0, stream>>>(x1_nets, pe_s, corr);
  k1_att_s<<<dim3(N_, S_), 512, 0, stream>>>(x, pe_s, Win_s, bin_s, x1_nets,
                                             alphas, betas, att0s, corr, att_s);
  k2_p1<<<dim3(N_, 16), 512, 0, stream>>>(x, att_s, Wout_s, bout_s, R1, partA);
  kred<<<128, 256, 0, stream>>>(partA, 4096, stats + 0);
  k3_p2<<<dim3(N_, 16), 512, 0, stream>>>(x, R1, Wff_s, bff_s, bnw1, bnb1, stats,
                                          R2, partA);
  kred<<<128, 256, 0, stream>>>(partA, 4096, stats + 128);
  k4a_yb<<<dim3(N_, 16), 512, 0, stream>>>(x, R2, bnw2, bnb2, stats, y_b, y_bT);
  k4b_qk<<<dim3(N_, 16), 512, 0, stream>>>(y_b, pe_t, Win_t, bin_t, R1);
  k5_att_t<<<dim3(N_, S_), 512, 0, stream>>>(R1, y_b, x1_nett, alphat, betat, att0t,
                                             att_t);
  k6_p3<<<dim3(N_, V_), 512, 0, stream>>>(y_bT, att_t, Wout_t, bout_t, R1, partB);
  kred<<<128, 256, 0, stream>>>(partB, 6400, stats + 256);
  k7_p4<<<dim3(N_, V_), 512, 0, stream>>>(y_bT, R1, Wff_t, bff_t, bnw3, bnb3, stats,
                                          R2, partA);
  kred<<<128, 256, 0, stream>>>(partA, 6400, stats + 384);
  k8_out<<<dim3(N_, 16), 512, 0, stream>>>(R2, bnw4, bnb4, stats, y_b);
}

// Round 9
// 3403.629 us; speedup vs baseline: 3.3629x; 1.3920x over previous
//
#include <hip/hip_runtime.h>

#define N_   256
#define C_   64
#define T_   64
#define V_   25
#define S_   3
#define IC_  16
#define TV_  1600
#define CTV_ 102400
#define NTVf 409600.0f
#define EPS  1e-5f

__device__ __forceinline__ float lrelu(float v) { return v >= 0.f ? v : 0.1f * v; }
__device__ __forceinline__ float dot4(float4 a, float4 b) {
  return a.x * b.x + a.y * b.y + a.z * b.z + a.w * b.w;
}
// swizzled slot offsets: row stride 64 floats (16 quads) / 32 floats (8 quads)
__device__ __forceinline__ int sw64(int row, int q) { return (q ^ (row & 15)) << 2; }
__device__ __forceinline__ int sw32(int row, int q) { return (q ^ (row & 7)) << 2; }

// -------- kred: stats[ch] = sum_i part[i*128 + ch], ch in [0,128)
__global__ __launch_bounds__(256) void kred(const float* __restrict__ part, int nblk,
                                            float* __restrict__ out) {
  int ch = blockIdx.x;
  float a = 0.f;
  for (int i = threadIdx.x; i < nblk; i += 256) a += part[i * 128 + ch];
  __shared__ float red[4];
#pragma unroll
  for (int off = 32; off > 0; off >>= 1) a += __shfl_down(a, off);
  if ((threadIdx.x & 63) == 0) red[threadIdx.x >> 6] = a;
  __syncthreads();
  if (threadIdx.x == 0) out[ch] = red[0] + red[1] + red[2] + red[3];
}

// -------- K0: corr[s,u,v] = sum_{c,t} x1_nets[s,c,t,u] * pe_s[c,t,v]
__global__ __launch_bounds__(256) void k0_corr(const float* __restrict__ x1s,
                                               const float* __restrict__ pe_s,
                                               float* __restrict__ corr) {
  int b = blockIdx.x; int s = b / V_, u = b % V_;
  float acc[V_];
#pragma unroll
  for (int v = 0; v < V_; ++v) acc[v] = 0.f;
  for (int idx = threadIdx.x; idx < C_ * T_; idx += 256) {
    float xv = x1s[(s * C_ * T_ + idx) * V_ + u];
    const float* per = pe_s + idx * V_;
#pragma unroll
    for (int v = 0; v < V_; ++v) acc[v] += xv * per[v];
  }
#pragma unroll
  for (int v = 0; v < V_; ++v) {
    float a = acc[v];
#pragma unroll
    for (int off = 32; off > 0; off >>= 1) a += __shfl_down(a, off);
    if ((threadIdx.x & 63) == 0) atomicAdd(&corr[(s * V_ + u) * V_ + v], a);
  }
}

// -------- K1: spatial attention, one block per (n,s). Register-tiled GEMMs.
__global__ __launch_bounds__(512) void k1_att_s(
    const float* __restrict__ x, const float* __restrict__ pe_s,
    const float* __restrict__ Win_s, const float* __restrict__ bin_s,
    const float* __restrict__ x1s, const float* __restrict__ alphas,
    const float* __restrict__ betas, const float* __restrict__ att0s,
    const float* __restrict__ corr, float* __restrict__ att_s_out) {
  int n = blockIdx.x, s = blockIdx.y, tid = threadIdx.x;
  int wave = tid >> 6, lane = tid & 63, li = lane >> 3, lj = lane & 7;
  __shared__ float wls[2048];                 // Win rows [r(32)][c(64)]
  __shared__ alignas(16) float xpeO[6400];    // [p][c-swz] for qk GEMM
  __shared__ alignas(16) float xq[2176];      // q-tile [u(32)][k(64)+pad4] k=ic*4+dt
  __shared__ alignas(16) float xk[2176];      // k-tile [v(32)][k]
  __shared__ alignas(16) float xAB[16640];    // xA=[u][k(256)+4] x1 ; xB same for xpe
  float* xA = xAB;
  float* xB = xAB + 8320;
  for (int idx = tid; idx < 2048; idx += 512) {
    int r = idx >> 6, c = idx & 63;
    int row = (r < IC_) ? (s * IC_ + r) : ((S_ + s) * IC_ + (r - IC_));
    wls[r * 64 + c] = Win_s[row * C_ + c];
  }
  // zero pad rows 25..31 (stay zero: staging only writes rows < 25)
  for (int idx = tid; idx < 7 * 260; idx += 512) {
    xA[25 * 260 + idx] = 0.f; xB[25 * 260 + idx] = 0.f;
  }
  for (int idx = tid; idx < 7 * 68; idx += 512) {
    xq[25 * 68 + idx] = 0.f; xk[25 * 68 + idx] = 0.f;
  }
  __syncthreads();
  // qk phase mapping: fixed row per thread, 16 threads share a row over p
  int qr = tid >> 4, qpp = tid & 15;
  int qrow = (qr < IC_) ? (s * IC_ + qr) : ((S_ + s) * IC_ + (qr - IC_));
  float qbias = bin_s[qrow];
  float4 wreg[16];
#pragma unroll
  for (int cq = 0; cq < 16; ++cq) wreg[cq] = *(const float4*)&wls[qr * 64 + cq * 4];
  float* qdst = (qr < IC_) ? xq : xk;
  int qrr = qr & 15;

  float a1acc[16], a2acc[16];
#pragma unroll
  for (int i = 0; i < 16; ++i) { a1acc[i] = 0.f; a2acc[i] = 0.f; }

  for (int t0 = 0; t0 < T_; t0 += 4) {
    __syncthreads();
    for (int idx = tid; idx < 6400; idx += 512) {
      int c = idx / 100, p = idx % 100, dt = p / 25, u = p % 25;
      int g = c * TV_ + t0 * V_ + p;
      float xpe = x[n * CTV_ + g] + pe_s[g];
      int k = c * 4 + dt;
      xB[u * 260 + k] = xpe;
      xA[u * 260 + k] = x1s[s * CTV_ + g];
      xpeO[p * 64 + sw64(p, c >> 2) + (c & 3)] = xpe;
    }
    __syncthreads();
    // qk: q/k rows into [u][ic*4+dt] layout
    for (int p = qpp; p < 100; p += 16) {
      float a = qbias;
#pragma unroll
      for (int cq = 0; cq < 16; ++cq)
        a += dot4(wreg[cq], *(const float4*)&xpeO[p * 64 + sw64(p, cq)]);
      int dt = p / 25, u = p % 25;
      qdst[u * 68 + qrr * 4 + dt] = a;
    }
    __syncthreads();
    // a2: K=256 split 8 waves x 8 quads
#pragma unroll
    for (int q8 = 0; q8 < 8; ++q8) {
      int kb = (wave * 8 + q8) * 4;
      float4 av[4], bv[4];
#pragma unroll
      for (int a = 0; a < 4; ++a) av[a] = *(const float4*)&xA[(li + 8 * a) * 260 + kb];
#pragma unroll
      for (int b = 0; b < 4; ++b) bv[b] = *(const float4*)&xB[(lj + 8 * b) * 260 + kb];
#pragma unroll
      for (int a = 0; a < 4; ++a)
#pragma unroll
        for (int b = 0; b < 4; ++b) a2acc[a * 4 + b] += dot4(av[a], bv[b]);
    }
    // a1: K=64 split 8 waves x 2 quads
#pragma unroll
    for (int q2 = 0; q2 < 2; ++q2) {
      int kb = (wave * 2 + q2) * 4;
      float4 av[4], bv[4];
#pragma unroll
      for (int a = 0; a < 4; ++a) av[a] = *(const float4*)&xq[(li + 8 * a) * 68 + kb];
#pragma unroll
      for (int b = 0; b < 4; ++b) bv[b] = *(const float4*)&xk[(lj + 8 * b) * 68 + kb];
#pragma unroll
      for (int a = 0; a < 4; ++a)
#pragma unroll
        for (int b = 0; b < 4; ++b) a1acc[a * 4 + b] += dot4(av[a], bv[b]);
    }
  }
  // cross-wave reduction (reuse xAB; stride 33 to dodge write conflicts)
  __syncthreads();
#pragma unroll
  for (int a = 0; a < 4; ++a)
#pragma unroll
    for (int b = 0; b < 4; ++b)
      xAB[wave * 1056 + (li + 8 * a) * 33 + (lj + 8 * b)] = a2acc[a * 4 + b];
  __syncthreads();
  float a2sum[2] = {0.f, 0.f};
#pragma unroll
  for (int k = 0; k < 2; ++k) {
    int o = tid + k * 512;
    if (o < 625) {
      int u = o / 25, v = o % 25;
      float sm = 0.f;
#pragma unroll
      for (int w = 0; w < 8; ++w) sm += xAB[w * 1056 + u * 33 + v];
      a2sum[k] = sm;
    }
  }
  __syncthreads();
#pragma unroll
  for (int a = 0; a < 4; ++a)
#pragma unroll
    for (int b = 0; b < 4; ++b)
      xAB[wave * 1056 + (li + 8 * a) * 33 + (lj + 8 * b)] = a1acc[a * 4 + b];
  __syncthreads();
  float al = alphas[s], be = betas[s];
#pragma unroll
  for (int k = 0; k < 2; ++k) {
    int o = tid + k * 512;
    if (o < 625) {
      int u = o / 25, v = o % 25;
      float sm = 0.f;
#pragma unroll
      for (int w = 0; w < 8; ++w) sm += xAB[w * 1056 + u * 33 + v];
      float a = tanhf(sm * (1.f / 1024.f)) * al
              + tanhf(a2sum[k] - corr[s * 625 + o]) * be
              + att0s[s * 625 + o];
      att_s_out[(n * S_ + s) * 625 + o] = a;
    }
  }
}

// -------- K2: p1 = Wout_s @ (x (x) att_s) + bout_s ; partial stats
__global__ __launch_bounds__(512) void k2_p1(
    const float* __restrict__ x, const float* __restrict__ att_s,
    const float* __restrict__ Wout_s, const float* __restrict__ bout_s,
    float* __restrict__ p1, float* __restrict__ part) {
  int n = blockIdx.x, t0 = blockIdx.y * 4, tid = threadIdx.x;
  __shared__ alignas(16) float xc2[64 * 112];   // [c][t*28+u] broadcast rows
  __shared__ alignas(16) float attT[25 * 32];   // [v][u-swz]
  __shared__ alignas(16) float xaT[100 * 68];   // [p][c]
  __shared__ alignas(16) float wl[64 * 68];     // [o][c]
  for (int idx = tid; idx < 6400; idx += 512) {
    int c = idx / 100, p = idx % 100, t = p / 25, u = p % 25;
    xc2[c * 112 + t * 28 + u] = x[n * CTV_ + c * TV_ + t0 * V_ + p];
  }
  int o = tid >> 3, pb = tid & 7;
  float acc[13];
#pragma unroll
  for (int j = 0; j < 13; ++j) acc[j] = 0.f;
  for (int s = 0; s < S_; ++s) {
    __syncthreads();
    for (int idx = tid; idx < 625; idx += 512) {
      int u = idx / 25, vv = idx % 25;
      attT[vv * 32 + sw32(vv, u >> 2) + (u & 3)] = att_s[n * 1875 + s * 625 + idx];
    }
    for (int idx = tid; idx < 4096; idx += 512) {
      int oo = idx >> 6, c = idx & 63;
      wl[oo * 68 + c] = Wout_s[oo * (S_ * C_) + s * C_ + c];
    }
    __syncthreads();
    for (int idx = tid; idx < 6400; idx += 512) {
      int c = idx / 100, p = idx % 100, t = p / 25, v = p % 25;
      const float* xr = &xc2[c * 112 + t * 28];
      const float* ar = &attT[v * 32];
      float a = 0.f;
#pragma unroll
      for (int uq = 0; uq < 6; ++uq)
        a += dot4(*(const float4*)&xr[uq * 4], *(const float4*)&ar[sw32(v, uq)]);
      a += xr[24] * ar[sw32(v, 6)];
      xaT[p * 68 + c] = a;
    }
    __syncthreads();
#pragma unroll
    for (int cq = 0; cq < 16; ++cq) {
      float4 w4 = *(const float4*)&wl[o * 68 + cq * 4];
#pragma unroll
      for (int j = 0; j < 13; ++j) {
        int p = pb + 8 * j;
        if (p < 100)
          acc[j] += dot4(w4, *(const float4*)&xaT[p * 68 + cq * 4]);
      }
    }
  }
  float b = bout_s[o], lsum = 0.f, lsq = 0.f;
  float* prow = p1 + n * CTV_ + o * TV_ + t0 * V_;
#pragma unroll
  for (int j = 0; j < 13; ++j) {
    int p = pb + 8 * j;
    if (p < 100) {
      float v = acc[j] + b;
      prow[p] = v;
      lsum += v; lsq += v * v;
    }
  }
  lsum += __shfl_down(lsum, 4); lsum += __shfl_down(lsum, 2); lsum += __shfl_down(lsum, 1);
  lsq  += __shfl_down(lsq, 4);  lsq  += __shfl_down(lsq, 2);  lsq  += __shfl_down(lsq, 1);
  if (pb == 0) {
    int bid = blockIdx.x * 16 + blockIdx.y;
    part[bid * 128 + o] = lsum;
    part[bid * 128 + 64 + o] = lsq;
  }
}

// -------- K3: y_a = lrelu(x + bn1(p1)); p2 = Wff_s @ y_a + bff_s; partial stats
__global__ __launch_bounds__(512) void k3_p2(
    const float* __restrict__ x, const float* __restrict__ p1,
    const float* __restrict__ Wff_s, const float* __restrict__ bff_s,
    const float* __restrict__ bnw1, const float* __restrict__ bnb1,
    const float* __restrict__ stats, float* __restrict__ p2,
    float* __restrict__ part) {
  int n = blockIdx.x, t0 = blockIdx.y * 4, tid = threadIdx.x;
  __shared__ alignas(16) float yaT[100 * 68];
  __shared__ alignas(16) float wl[64 * 68];
  __shared__ float sc[64], sh[64];
  if (tid < 64) {
    float m = stats[tid] * (1.f / NTVf);
    float var = stats[64 + tid] * (1.f / NTVf) - m * m;
    float r = rsqrtf(var + EPS);
    float scl = bnw1[tid] * r;
    sc[tid] = scl; sh[tid] = bnb1[tid] - m * scl;
  }
  for (int idx = tid; idx < 4096; idx += 512) {
    int oo = idx >> 6, c = idx & 63;
    wl[oo * 68 + c] = Wff_s[idx];
  }
  __syncthreads();
  for (int idx = tid; idx < 6400; idx += 512) {
    int c = idx / 100, p = idx % 100;
    int g = n * CTV_ + c * TV_ + t0 * V_ + p;
    yaT[p * 68 + c] = lrelu(x[g] + p1[g] * sc[c] + sh[c]);
  }
  __syncthreads();
  int o = tid >> 3, pb = tid & 7;
  float acc[13];
#pragma unroll
  for (int j = 0; j < 13; ++j) acc[j] = 0.f;
#pragma unroll
  for (int cq = 0; cq < 16; ++cq) {
    float4 w4 = *(const float4*)&wl[o * 68 + cq * 4];
#pragma unroll
    for (int j = 0; j < 13; ++j) {
      int p = pb + 8 * j;
      if (p < 100)
        acc[j] += dot4(w4, *(const float4*)&yaT[p * 68 + cq * 4]);
    }
  }
  float b = bff_s[o], lsum = 0.f, lsq = 0.f;
  float* prow = p2 + n * CTV_ + o * TV_ + t0 * V_;
#pragma unroll
  for (int j = 0; j < 13; ++j) {
    int p = pb + 8 * j;
    if (p < 100) {
      float v = acc[j] + b;
      prow[p] = v;
      lsum += v; lsq += v * v;
    }
  }
  lsum += __shfl_down(lsum, 4); lsum += __shfl_down(lsum, 2); lsum += __shfl_down(lsum, 1);
  lsq  += __shfl_down(lsq, 4);  lsq  += __shfl_down(lsq, 2);  lsq  += __shfl_down(lsq, 1);
  if (pb == 0) {
    int bid = blockIdx.x * 16 + blockIdx.y;
    part[bid * 128 + o] = lsum;
    part[bid * 128 + 64 + o] = lsq;
  }
}

// -------- K4a: y_b = lrelu(x + bn2(p2)) -> d_out (y_b) and transposed y_bT
__global__ __launch_bounds__(512) void k4a_yb(
    const float* __restrict__ x, const float* __restrict__ p2,
    const float* __restrict__ bnw2, const float* __restrict__ bnb2,
    const float* __restrict__ stats,
    float* __restrict__ y_b, float* __restrict__ y_bT) {
  int n = blockIdx.x, t0 = blockIdx.y * 4, tid = threadIdx.x;
  __shared__ float yb[64 * 101];
  __shared__ float sc[64], sh[64];
  if (tid < 64) {
    float m = stats[128 + tid] * (1.f / NTVf);
    float var = stats[192 + tid] * (1.f / NTVf) - m * m;
    float r = rsqrtf(var + EPS);
    float scl = bnw2[tid] * r;
    sc[tid] = scl; sh[tid] = bnb2[tid] - m * scl;
  }
  __syncthreads();
  for (int idx = tid; idx < 6400; idx += 512) {
    int c = idx / 100, p = idx % 100;
    int g = n * CTV_ + c * TV_ + t0 * V_ + p;
    float v = lrelu(x[g] + p2[g] * sc[c] + sh[c]);
    yb[c * 101 + p] = v;
    y_b[g] = v;
  }
  __syncthreads();
  for (int idx = tid; idx < 1600; idx += 512) {
    int v = idx >> 6, c = idx & 63;
    const float* yr = yb + c * 101 + v;
    float4 w4 = make_float4(yr[0], yr[25], yr[50], yr[75]);
    *(float4*)(y_bT + n * CTV_ + v * 4096 + c * 64 + t0) = w4;
  }
}

// -------- K4b: qk_all[n][r(96)][t][v], all 3 subnets in one pass
__global__ __launch_bounds__(512) void k4b_qk(
    const float* __restrict__ y_b, const float* __restrict__ pe_t,
    const float* __restrict__ Win_t, const float* __restrict__ bin_t,
    float* __restrict__ qk_all) {
  int n = blockIdx.x, t0 = blockIdx.y * 4, tid = threadIdx.x;
  __shared__ alignas(16) float ypeT[6400];  // [p][c-swz]
  __shared__ alignas(16) float wlt[6144];   // [r(96)][c]
  for (int idx = tid; idx < 6144; idx += 512) wlt[idx] = Win_t[idx];
  for (int idx = tid; idx < 6400; idx += 512) {
    int c = idx / 100, p = idx % 100;
    int gg = c * TV_ + t0 * V_ + p;
    ypeT[p * 64 + sw64(p, c >> 2) + (c & 3)] = y_b[n * CTV_ + gg] + pe_t[gg];
  }
  __syncthreads();
  for (int idx = tid; idx < 9600; idx += 512) {
    int r = idx / 100, p = idx % 100;
    float a = bin_t[r];
#pragma unroll
    for (int cq = 0; cq < 16; ++cq)
      a += dot4(*(const float4*)&wlt[r * 64 + cq * 4],
                *(const float4*)&ypeT[p * 64 + sw64(p, cq)]);
    qk_all[n * 153600 + r * TV_ + t0 * V_ + p] = a;
  }
}

// -------- K5: temporal attention, one block per (n,s). 4x4 register tiling.
__global__ __launch_bounds__(512) void k5_att_t(
    const float* __restrict__ qk_all, const float* __restrict__ y_b,
    const float* __restrict__ x1t, const float* __restrict__ alphat,
    const float* __restrict__ betat, const float* __restrict__ att0t,
    float* __restrict__ att_t_out) {
  int n = blockIdx.x, s = blockIdx.y, tid = threadIdx.x;
  int wave = tid >> 6, lane = tid & 63, li = lane >> 3, lj = lane & 7;
  int wq = wave & 1, wt = (wave >> 1) & 1, kh = wave >> 2;
  int tb = wt * 32 + li, qb = wq * 32 + lj;
  __shared__ alignas(16) float A[6400], B[6400];  // [row(64)][k(100)]
  float acc1[16], acc2[16];
#pragma unroll
  for (int i = 0; i < 16; ++i) { acc1[i] = 0.f; acc2[i] = 0.f; }
  // phase 1: acc1[t][q] = sum_{ic,v} q[ic,t,v]*k[ic,q,v]; 4 chunks of 4 ic
  for (int ch = 0; ch < 4; ++ch) {
    __syncthreads();
    const float* qs = qk_all + n * 153600 + (s * IC_ + ch * 4) * TV_;
    const float* ks = qk_all + n * 153600 + (S_ * IC_ + s * IC_ + ch * 4) * TV_;
    for (int idx = tid; idx < 6400; idx += 512) {
      int cp = idx / 1600, rem = idx % 1600, t = rem / 25, v = rem % 25;
      int a = t * 100 + cp * 25 + v;
      A[a] = qs[idx];
      B[a] = ks[idx];
    }
    __syncthreads();
    int lo = kh ? 12 : 0, hi = kh ? 25 : 12;
    for (int qd = lo; qd < hi; ++qd) {
      int kb = qd * 4;
      float4 av[4], bv[4];
#pragma unroll
      for (int a = 0; a < 4; ++a) av[a] = *(const float4*)&A[(tb + 8 * a) * 100 + kb];
#pragma unroll
      for (int b = 0; b < 4; ++b) bv[b] = *(const float4*)&B[(qb + 8 * b) * 100 + kb];
#pragma unroll
      for (int a = 0; a < 4; ++a)
#pragma unroll
        for (int b = 0; b < 4; ++b) acc1[a * 4 + b] += dot4(av[a], bv[b]);
    }
  }
  // phase 2: acc2[t][q] = sum_{c,v} x1t[s,c,t,v]*y[n,c,q,v]; 16 chunks of 4 c
  for (int ch = 0; ch < 16; ++ch) {
    __syncthreads();
    const float* as = x1t + s * CTV_ + ch * 4 * TV_;
    const float* bs = y_b + n * CTV_ + ch * 4 * TV_;
    for (int idx = tid; idx < 6400; idx += 512) {
      int cp = idx / 1600, rem = idx % 1600, t = rem / 25, v = rem % 25;
      int a = t * 100 + cp * 25 + v;
      A[a] = as[idx];
      B[a] = bs[idx];
    }
    __syncthreads();
    int lo = kh ? 12 : 0, hi = kh ? 25 : 12;
    for (int qd = lo; qd < hi; ++qd) {
      int kb = qd * 4;
      float4 av[4], bv[4];
#pragma unroll
      for (int a = 0; a < 4; ++a) av[a] = *(const float4*)&A[(tb + 8 * a) * 100 + kb];
#pragma unroll
      for (int b = 0; b < 4; ++b) bv[b] = *(const float4*)&B[(qb + 8 * b) * 100 + kb];
#pragma unroll
      for (int a = 0; a < 4; ++a)
#pragma unroll
        for (int b = 0; b < 4; ++b) acc2[a * 4 + b] += dot4(av[a], bv[b]);
    }
  }
  // K-half reduction: waves 4..7 -> LDS (stride 33), waves 0..3 combine + finalize
  __syncthreads();
  if (kh) {
#pragma unroll
    for (int a = 0; a < 4; ++a)
#pragma unroll
      for (int b = 0; b < 4; ++b)
        A[(wave - 4) * 1056 + (li + 8 * a) * 33 + (lj + 8 * b)] = acc2[a * 4 + b];
  }
  __syncthreads();
  if (!kh) {
#pragma unroll
    for (int a = 0; a < 4; ++a)
#pragma unroll
      for (int b = 0; b < 4; ++b)
        acc2[a * 4 + b] += A[wave * 1056 + (li + 8 * a) * 33 + (lj + 8 * b)];
  }
  __syncthreads();
  if (kh) {
#pragma unroll
    for (int a = 0; a < 4; ++a)
#pragma unroll
      for (int b = 0; b < 4; ++b)
        A[(wave - 4) * 1056 + (li + 8 * a) * 33 + (lj + 8 * b)] = acc1[a * 4 + b];
  }
  __syncthreads();
  if (!kh) {
    float al = alphat[s], be = betat[s];
#pragma unroll
    for (int a = 0; a < 4; ++a)
#pragma unroll
      for (int b = 0; b < 4; ++b) {
        float a1 = acc1[a * 4 + b] + A[wave * 1056 + (li + 8 * a) * 33 + (lj + 8 * b)];
        int t = tb + 8 * a, q = qb + 8 * b;
        int o = t * 64 + q;
        float val = tanhf(a1 * (1.f / 400.f)) * al + tanhf(acc2[a * 4 + b]) * be
                  + att0t[s * 4096 + o];
        att_t_out[(n * S_ + s) * 4096 + o] = val;
      }
  }
}

// -------- K6 v2: grid (N,5); 5 v's per block; float4 staging; weights restaged per (v,s)
__global__ __launch_bounds__(512) void k6_p3(
    const float* __restrict__ y_bT, const float* __restrict__ att_t,
    const float* __restrict__ Wout_t, const float* __restrict__ bout_t,
    float* __restrict__ p3T, float* __restrict__ part) {
  int n = blockIdx.x, v0 = blockIdx.y * 5, tid = threadIdx.x;
  int q = tid & 63, w8 = tid >> 6;
  int ic = tid >> 3, it = (tid & 7) * 8;     // thread owns elems tid*8..tid*8+7
  __shared__ alignas(16) float yl[64 * 68];  // Y[c][t]
  __shared__ alignas(16) float aT[64 * 64];  // A^T [q][t-swz]
  __shared__ alignas(16) float wl[64 * 68];  // W[o][c]
  __shared__ alignas(16) float zsT[64 * 64]; // Z^T [q][c-swz]
  float pls[8], plq[8];
#pragma unroll
  for (int j = 0; j < 8; ++j) { pls[j] = 0.f; plq[j] = 0.f; }
  for (int vv = 0; vv < 5; ++vv) {
    int v = v0 + vv;
    __syncthreads();
    {
      const float* src = y_bT + n * CTV_ + v * 4096 + tid * 8;
      float4 a4 = *(const float4*)src;
      float4 b4 = *(const float4*)(src + 4);
      *(float4*)&yl[ic * 68 + it] = a4;       // yl[c=ic][t=it..it+7]
      *(float4*)&yl[ic * 68 + it + 4] = b4;
    }
    float acc[8];
#pragma unroll
    for (int j = 0; j < 8; ++j) acc[j] = 0.f;
    for (int s = 0; s < S_; ++s) {
      __syncthreads();
      {
        const float* asrc = att_t + (n * S_ + s) * 4096 + tid * 8;  // [t=ic][q=it+e]
        const float* wsrc = Wout_t + ic * 192 + s * 64 + it;
        float4 w4a = *(const float4*)wsrc;
        float4 w4b = *(const float4*)(wsrc + 4);
        *(float4*)&wl[ic * 68 + it] = w4a;
        *(float4*)&wl[ic * 68 + it + 4] = w4b;
#pragma unroll
        for (int e = 0; e < 8; ++e) {
          int qq = it + e;
          aT[qq * 64 + sw64(qq, ic >> 2) + (ic & 3)] = asrc[e];
        }
      }
      __syncthreads();
      // GEMM1: Z[c][q] = sum_t Y[c][t]*A[t][q]
      float accz[8];
#pragma unroll
      for (int k = 0; k < 8; ++k) accz[k] = 0.f;
#pragma unroll
      for (int tq = 0; tq < 16; ++tq) {
        float4 a4 = *(const float4*)&aT[q * 64 + sw64(q, tq)];
#pragma unroll
        for (int k = 0; k < 8; ++k)
          accz[k] += dot4(*(const float4*)&yl[(w8 + 8 * k) * 68 + tq * 4], a4);
      }
#pragma unroll
      for (int k = 0; k < 8; ++k) {
        int c = w8 + 8 * k;
        zsT[q * 64 + sw64(q, c >> 2) + (c & 3)] = accz[k];
      }
      __syncthreads();
      // GEMM2: acc[j] += sum_c W[o][c] * Z[c][q]
#pragma unroll
      for (int cq = 0; cq < 16; ++cq) {
        float4 z4 = *(const float4*)&zsT[q * 64 + sw64(q, cq)];
#pragma unroll
        for (int j = 0; j < 8; ++j) {
          float4 w4 = *(const float4*)&wl[(w8 + 8 * j) * 68 + cq * 4];
          acc[j] += dot4(w4, z4);
        }
      }
    }
#pragma unroll
    for (int j = 0; j < 8; ++j) {
      int o = w8 + 8 * j;
      float val = acc[j] + bout_t[o];
      p3T[n * CTV_ + v * 4096 + o * 64 + q] = val;
      float ls = val, lq2 = val * val;
#pragma unroll
      for (int m = 32; m > 0; m >>= 1) { ls += __shfl_xor(ls, m); lq2 += __shfl_xor(lq2, m); }
      pls[j] += ls; plq[j] += lq2;
    }
  }
  if (q == 0) {
    int bid = blockIdx.x * 5 + blockIdx.y;
#pragma unroll
    for (int j = 0; j < 8; ++j) {
      int o = w8 + 8 * j;
      part[bid * 128 + o] = pls[j];
      part[bid * 128 + 64 + o] = plq[j];
    }
  }
}

// -------- K7 v2: grid (N,5); wl/sc/sh staged once; float4 loads + register prefetch
__global__ __launch_bounds__(512) void k7_p4(
    const float* __restrict__ y_bT, const float* __restrict__ p3T,
    const float* __restrict__ Wff_t, const float* __restrict__ bff_t,
    const float* __restrict__ bnw3, const float* __restrict__ bnb3,
    const float* __restrict__ stats, float* __restrict__ p4T,
    float* __restrict__ part) {
  int n = blockIdx.x, v0 = blockIdx.y * 5, tid = threadIdx.x;
  int q = tid & 63, w8 = tid >> 6;
  int ic = tid >> 3, it = (tid & 7) * 8;
  __shared__ alignas(16) float zaT[64 * 64];  // [t][c-swz]
  __shared__ alignas(16) float wl[64 * 68];   // [o][c]
  __shared__ float sc[64], sh[64];
  if (tid < 64) {
    float m = stats[256 + tid] * (1.f / NTVf);
    float var = stats[320 + tid] * (1.f / NTVf) - m * m;
    float r = rsqrtf(var + EPS);
    float scl = bnw3[tid] * r;
    sc[tid] = scl; sh[tid] = bnb3[tid] - m * scl;
  }
  {
    const float* wsrc = Wff_t + tid * 8;
    float4 w4a = *(const float4*)wsrc;
    float4 w4b = *(const float4*)(wsrc + 4);
    *(float4*)&wl[ic * 68 + it] = w4a;
    *(float4*)&wl[ic * 68 + it + 4] = w4b;
  }
  float bffr[8];
#pragma unroll
  for (int j = 0; j < 8; ++j) bffr[j] = bff_t[w8 + 8 * j];
  const float* ybase = y_bT + n * CTV_ + v0 * 4096 + tid * 8;
  const float* pbase = p3T + n * CTV_ + v0 * 4096 + tid * 8;
  float4 y0 = *(const float4*)ybase;
  float4 y1 = *(const float4*)(ybase + 4);
  float4 p0 = *(const float4*)pbase;
  float4 p1 = *(const float4*)(pbase + 4);
  __syncthreads();
  float pls[8], plq[8];
#pragma unroll
  for (int j = 0; j < 8; ++j) { pls[j] = 0.f; plq[j] = 0.f; }
  for (int vv = 0; vv < 5; ++vv) {
    float scc = sc[ic], shh = sh[ic];
    float za[8];
    za[0] = lrelu(y0.x + p0.x * scc + shh);
    za[1] = lrelu(y0.y + p0.y * scc + shh);
    za[2] = lrelu(y0.z + p0.z * scc + shh);
    za[3] = lrelu(y0.w + p0.w * scc + shh);
    za[4] = lrelu(y1.x + p1.x * scc + shh);
    za[5] = lrelu(y1.y + p1.y * scc + shh);
    za[6] = lrelu(y1.z + p1.z * scc + shh);
    za[7] = lrelu(y1.w + p1.w * scc + shh);
#pragma unroll
    for (int e = 0; e < 8; ++e) {
      int t = it + e;
      zaT[t * 64 + sw64(t, ic >> 2) + (ic & 3)] = za[e];
    }
    if (vv < 4) {  // prefetch next v while GEMM runs
      int off = (vv + 1) * 4096;
      y0 = *(const float4*)(ybase + off);
      y1 = *(const float4*)(ybase + off + 4);
      p0 = *(const float4*)(pbase + off);
      p1 = *(const float4*)(pbase + off + 4);
    }
    __syncthreads();
    float acc[8];
#pragma unroll
    for (int j = 0; j < 8; ++j) acc[j] = bffr[j];
#pragma unroll
    for (int cq = 0; cq < 16; ++cq) {
      float4 zq = *(const float4*)&zaT[q * 64 + sw64(q, cq)];
#pragma unroll
      for (int j = 0; j < 8; ++j) {
        float4 w4 = *(const float4*)&wl[(w8 + 8 * j) * 68 + cq * 4];
        acc[j] += dot4(w4, zq);
      }
    }
#pragma unroll
    for (int j = 0; j < 8; ++j) {
      int o = w8 + 8 * j;
      float val = acc[j];
      p4T[n * CTV_ + (v0 + vv) * 4096 + o * 64 + q] = val;
      float ls = val, lq2 = val * val;
#pragma unroll
      for (int m = 32; m > 0; m >>= 1) { ls += __shfl_xor(ls, m); lq2 += __shfl_xor(lq2, m); }
      pls[j] += ls; plq[j] += lq2;
    }
    __syncthreads();
  }
  if (q == 0) {
    int bid = blockIdx.x * 5 + blockIdx.y;
#pragma unroll
    for (int j = 0; j < 8; ++j) {
      int o = w8 + 8 * j;
      part[bid * 128 + o] = pls[j];
      part[bid * 128 + 64 + o] = plq[j];
    }
  }
}

// -------- K8: out = lrelu(y_b + bn4(p4)) with LDS transpose back, in-place
__global__ __launch_bounds__(512) void k8_out(
    const float* __restrict__ p4T, const float* __restrict__ bnw4,
    const float* __restrict__ bnb4, const float* __restrict__ stats,
    float* __restrict__ out) {
  int n = blockIdx.x, ct0 = blockIdx.y * 256, tid = threadIdx.x;
  __shared__ float tile[25 * 257];
  __shared__ float sc[64], sh[64];
  if (tid < 64) {
    float m = stats[384 + tid] * (1.f / NTVf);
    float var = stats[448 + tid] * (1.f / NTVf) - m * m;
    float r = rsqrtf(var + EPS);
    float scl = bnw4[tid] * r;
    sc[tid] = scl; sh[tid] = bnb4[tid] - m * scl;
  }
  for (int idx = tid; idx < 6400; idx += 512) {
    int v = idx >> 8, ctl = idx & 255;
    tile[v * 257 + ctl] = p4T[n * CTV_ + v * 4096 + ct0 + ctl];
  }
  __syncthreads();
  float* base = out + n * CTV_ + ct0 * 25;
  for (int idx = tid; idx < 6400; idx += 512) {
    int ctl = idx / 25, vv = idx % 25;
    int c = (ct0 + ctl) >> 6;
    float val = base[idx] + tile[vv * 257 + ctl] * sc[c] + sh[c];
    base[idx] = lrelu(val);
  }
}

extern "C" void kernel_launch(void* const* d_in, const int* in_sizes, int n_in,
                              void* d_out, int out_size, void* d_ws, size_t ws_size,
                              hipStream_t stream) {
  // setup_inputs() DICT order (pe_t is index 2!)
  const float* x       = (const float*)d_in[0];
  const float* pe_s    = (const float*)d_in[1];
  const float* pe_t    = (const float*)d_in[2];
  const float* Win_s   = (const float*)d_in[3];
  const float* bin_s   = (const float*)d_in[4];
  const float* alphas  = (const float*)d_in[5];
  const float* x1_nets = (const float*)d_in[6];
  const float* betas   = (const float*)d_in[7];
  const float* att0s   = (const float*)d_in[8];
  const float* Wout_s  = (const float*)d_in[9];
  const float* bout_s  = (const float*)d_in[10];
  const float* bnw1    = (const float*)d_in[11];
  const float* bnb1    = (const float*)d_in[12];
  const float* Wff_s   = (const float*)d_in[13];
  const float* bff_s   = (const float*)d_in[14];
  const float* bnw2    = (const float*)d_in[15];
  const float* bnb2    = (const float*)d_in[16];
  const float* Win_t   = (const float*)d_in[17];
  const float* bin_t   = (const float*)d_in[18];
  const float* alphat  = (const float*)d_in[19];
  const float* x1_nett = (const float*)d_in[20];
  const float* betat   = (const float*)d_in[21];
  const float* att0t   = (const float*)d_in[22];
  const float* Wout_t  = (const float*)d_in[23];
  const float* bout_t  = (const float*)d_in[24];
  const float* bnw3    = (const float*)d_in[25];
  const float* bnb3    = (const float*)d_in[26];
  const float* Wff_t   = (const float*)d_in[27];
  const float* bff_t   = (const float*)d_in[28];
  const float* bnw4    = (const float*)d_in[29];
  const float* bnb4    = (const float*)d_in[30];

  if (n_in < 31) return;
  if (in_sizes[0] != N_ * CTV_) return;
  if (in_sizes[2] != CTV_) return;
  if (in_sizes[3] != 2 * S_ * IC_ * C_) return;
  if (in_sizes[6] != S_ * CTV_) return;
  if (in_sizes[9] != C_ * S_ * C_) return;

  float* ws = (float*)d_ws;
  const size_t off_att_s = 0;
  const size_t off_att_t = 480000;               // 3,145,728 floats
  const size_t off_corr  = off_att_t + 3145728;
  const size_t off_stats = off_corr + 1875;
  const size_t off_R1    = 3628160;
  const size_t off_R2    = off_R1 + 26214400;
  const size_t off_R3    = off_R2 + 26214400;
  const size_t need      = (off_R3 + 26214400) * sizeof(float);
  if (ws_size < need) return;

  float* att_s = ws + off_att_s;
  float* att_t = ws + off_att_t;
  float* corr  = ws + off_corr;
  float* stats = ws + off_stats;
  float* R1    = ws + off_R1;   // p1, then qk_all (spans R1+13.1M of R2), then p3T
  float* R2    = ws + off_R2;   // p2, then tail of qk_all / partB, then p4T
  float* y_bT  = ws + off_R3;
  float* y_b   = (float*)d_out;
  float* partA = att_t;         // stats stages 0,1 (att_t unwritten) and 3 (att_t dead)
  float* partB = R2;            // stats stage 2 (qk_all tail dead after k5)

  hipMemsetAsync(corr, 0, 1875 * sizeof(float), stream);
  k0_corr<<<dim3(S_ * V_), 256, 0, stream>>>(x1_nets, pe_s, corr);
  k1_att_s<<<dim3(N_, S_), 512, 0, stream>>>(x, pe_s, Win_s, bin_s, x1_nets,
                                             alphas, betas, att0s, corr, att_s);
  k2_p1<<<dim3(N_, 16), 512, 0, stream>>>(x, att_s, Wout_s, bout_s, R1, partA);
  kred<<<128, 256, 0, stream>>>(partA, 4096, stats + 0);
  k3_p2<<<dim3(N_, 16), 512, 0, stream>>>(x, R1, Wff_s, bff_s, bnw1, bnb1, stats,
                                          R2, partA);
  kred<<<128, 256, 0, stream>>>(partA, 4096, stats + 128);
  k4a_yb<<<dim3(N_, 16), 512, 0, stream>>>(x, R2, bnw2, bnb2, stats, y_b, y_bT);
  k4b_qk<<<dim3(N_, 16), 512, 0, stream>>>(y_b, pe_t, Win_t, bin_t, R1);
  k5_att_t<<<dim3(N_, S_), 512, 0, stream>>>(R1, y_b, x1_nett, alphat, betat, att0t,
                                             att_t);
  k6_p3<<<dim3(N_, 5), 512, 0, stream>>>(y_bT, att_t, Wout_t, bout_t, R1, partB);
  kred<<<128, 256, 0, stream>>>(partB, 1280, stats + 256);
  k7_p4<<<dim3(N_, 5), 512, 0, stream>>>(y_bT, R1, Wff_t, bff_t, bnw3, bnb3, stats,
                                         R2, partA);
  kred<<<128, 256, 0, stream>>>(partA, 1280, stats + 384);
  k8_out<<<dim3(N_, 16), 512, 0, stream>>>(R2, bnw4, bnb4, stats, y_b);
}